// Round 19
// baseline (347.229 us; speedup 1.0000x reference)
//
#include <hip/hip_runtime.h>
#include <hip/hip_bf16.h>
#include <math.h>

// Problem constants
#define B_   8
#define D_   384
#define DC_  1024
#define NH_  8
#define NP_  4
#define DH_  48
#define NQ_  4096
#define NT_  730
#define NG_  729
#define GW_  27

typedef unsigned short u16;
typedef __attribute__((ext_vector_type(8))) short s8bf;   // 8 bf16 (4 VGPR)
typedef __attribute__((ext_vector_type(4))) float f32x4;  // MFMA accumulator

__device__ __forceinline__ float bf2f(u16 u) { return __uint_as_float(((unsigned)u) << 16); }
__device__ __forceinline__ u16 f2bf(float f) {
    __hip_bfloat16 h = __float2bfloat16(f);
    return *reinterpret_cast<u16*>(&h);
}
__device__ __forceinline__ float rd(const float* p) { return *p; }
__device__ __forceinline__ float rd(const u16* p)   { return bf2f(*p); }
__device__ __forceinline__ void  wr(float* p, float v) { *p = v; }
__device__ __forceinline__ void  wr(u16* p, float v)   { *p = f2bf(v); }
__device__ __forceinline__ void fmacc4(float4& o, const float4 v, float w) {
    o.x = fmaf(v.x, w, o.x); o.y = fmaf(v.y, w, o.y);
    o.z = fmaf(v.z, w, o.z); o.w = fmaf(v.w, w, o.w);
}
__device__ __forceinline__ int imin(int a, int b) { return a < b ? a : b; }
// tanh-form GELU (r11; dev vs exact erf-gelu ~3e-3, damped by gate~0.007)
__device__ __forceinline__ float fast_gelu(float x) {
    float z = 1.5957691216057308f * fmaf(0.044715f * x, x * x, x);
    return x / (1.f + __expf(-z));
}
__device__ __forceinline__ float fast_sigmoid(float x) {
    return 1.f / (1.f + __expf(-x));
}

// async 16B global->LDS (dest = wave-uniform base + lane*16)
#define GLOAD16(gp, lp) \
    __builtin_amdgcn_global_load_lds( \
        (const __attribute__((address_space(1))) void*)(gp), \
        (__attribute__((address_space(3))) void*)(lp), 16, 0, 0)

// ---------------------------------------------------------------------------
// Fused visual transpose + LayerNorm: visual f32 [B,384,4096] ->
// vflat bf16 [B,4096,384] (raw) AND vn bf16 (LN'd). One block = 32 queries.
// ---------------------------------------------------------------------------
__global__ __launch_bounds__(256) void tr_ln_kernel(
    const float* __restrict__ visual,
    const float* __restrict__ g, const float* __restrict__ be,
    u16* __restrict__ vflat, u16* __restrict__ vn)
{
    __shared__ float lds[D_][33];
    __shared__ float sM[32], sR[32];
    const int blk = blockIdx.x;
    const int b = blk >> 7, q0 = (blk & 127) << 5;
    const int t = threadIdx.x;
    const int tx = t & 31, ty = t >> 5;
    const float* vb = visual + (size_t)b * D_ * NQ_ + q0;
#pragma unroll
    for (int ct = 0; ct < 12; ++ct)
#pragma unroll
        for (int i = 0; i < 32; i += 8) {
            const int c = ct * 32 + ty + i;
            lds[c][tx] = vb[(size_t)c * NQ_ + tx];
        }
    __syncthreads();
    const int wv = t >> 6, lane = t & 63;
    for (int k = 0; k < 8; ++k) {
        const int q = wv * 8 + k;
        float s = 0.f, ss = 0.f;
#pragma unroll
        for (int e = 0; e < 6; ++e) {
            float v = lds[lane * 6 + e][q];
            s += v; ss += v * v;
        }
#pragma unroll
        for (int o = 32; o > 0; o >>= 1) { s += __shfl_down(s, o); ss += __shfl_down(ss, o); }
        if (lane == 0) {
            float m = s / (float)D_;
            sM[q] = m; sR[q] = rsqrtf(ss / (float)D_ - m * m + 1e-5f);
        }
    }
    __syncthreads();
    for (int idx = t; idx < 32 * D_; idx += 256) {
        const int q = idx / D_, c = idx % D_;
        const float raw = lds[c][q];
        const size_t row = (size_t)b * NQ_ + q0 + q;
        vflat[row * D_ + c] = f2bf(raw);
        vn[row * D_ + c]    = f2bf((raw - sM[q]) * sR[q] * g[c] + be[c]);
    }
}

// ---------------------------------------------------------------------------
// Fused output LN + transpose (r18): x = vflat + gate*ffn; LN(ln_o);
// write d_out f32 [B,384,4096] DIRECTLY (transposed).
// ---------------------------------------------------------------------------
__global__ __launch_bounds__(256) void fused_ln_tr_kernel(
    const u16* __restrict__ vflat, const float* __restrict__ gate,
    const u16* __restrict__ ffn,
    const float* __restrict__ g, const float* __restrict__ be,
    float* __restrict__ outT)
{
    __shared__ float buf[D_][33];
    __shared__ float sM[32], sR[32], sG[32];
    const int blk = blockIdx.x;
    const int b = blk >> 7, q0 = (blk & 127) << 5;
    const int t = threadIdx.x;
    const int tx = t & 31, ty = t >> 5;
    if (t < 32) sG[t] = gate[(size_t)b * NQ_ + q0 + t];
    __syncthreads();
    for (int idx = t; idx < 32 * D_; idx += 256) {
        const int q = idx / D_, c = idx % D_;
        const size_t row = (size_t)b * NQ_ + q0 + q;
        buf[c][q] = bf2f(vflat[row * D_ + c]) + sG[q] * bf2f(ffn[row * D_ + c]);
    }
    __syncthreads();
    const int wv = t >> 6, lane = t & 63;
    for (int k = 0; k < 8; ++k) {
        const int q = wv * 8 + k;
        float s = 0.f, ss = 0.f;
#pragma unroll
        for (int e = 0; e < 6; ++e) {
            float v = buf[lane * 6 + e][q];
            s += v; ss += v * v;
        }
#pragma unroll
        for (int o = 32; o > 0; o >>= 1) { s += __shfl_down(s, o); ss += __shfl_down(ss, o); }
        if (lane == 0) {
            float m = s / (float)D_;
            sM[q] = m; sR[q] = rsqrtf(ss / (float)D_ - m * m + 1e-5f);
        }
    }
    __syncthreads();
    float* ob = outT + (size_t)b * D_ * NQ_ + q0;
#pragma unroll
    for (int ct = 0; ct < 12; ++ct)
#pragma unroll
        for (int i = 0; i < 32; i += 8) {
            const int c = ct * 32 + ty + i;
            ob[(size_t)c * NQ_ + tx] = (buf[c][tx] - sM[tx]) * sR[tx] * g[c] + be[c];
        }
}

// ---------------------------------------------------------------------------
// Merged weight conversion: 8 weights f32[K,N] -> bf16[N,K] in ONE launch.
// ---------------------------------------------------------------------------
struct WtD { const float* src; u16* dst; int R; int C; int start; };
struct WtArgs { WtD d[8]; };

__global__ __launch_bounds__(256) void wt_convert_kernel(WtArgs a)
{
    __shared__ float tile[32][33];
    const int bt = blockIdx.x;
    int wi = 0;
#pragma unroll
    for (int k = 1; k < 8; ++k) if (bt >= a.d[k].start) wi = k;
    const float* src = a.d[wi].src;
    u16*         dst = a.d[wi].dst;
    const int R = a.d[wi].R, C = a.d[wi].C;
    const int local = bt - a.d[wi].start;
    const int tilesX = C >> 5;
    const int c0 = (local % tilesX) << 5;
    const int r0 = (local / tilesX) << 5;
    const int tx = threadIdx.x & 31, ty = threadIdx.x >> 5;
#pragma unroll
    for (int i = 0; i < 32; i += 8)
        tile[ty + i][tx] = src[(size_t)(r0 + ty + i) * C + c0 + tx];
    __syncthreads();
#pragma unroll
    for (int i = 0; i < 32; i += 8)
        dst[(size_t)(c0 + ty + i) * R + r0 + tx] = f2bf(tile[tx][ty + i]);
}

// ---------------------------------------------------------------------------
// Row LayerNorm (cut3r only): f32 in [rows][width] -> bf16 out. block 256.
// ---------------------------------------------------------------------------
__global__ __launch_bounds__(256) void ln_kernel(
    const float* __restrict__ x, const float* __restrict__ g, const float* __restrict__ be,
    u16* __restrict__ out, int width)
{
    __shared__ float buf[1024];
    __shared__ float red[4][2];
    const size_t row = blockIdx.x;
    const float* xr = x + row * width;
    const int t = threadIdx.x;
    float s = 0.f, ss = 0.f;
    for (int i = t; i < width; i += 256) {
        float v = xr[i]; buf[i] = v; s += v; ss += v * v;
    }
#pragma unroll
    for (int o = 32; o > 0; o >>= 1) { s += __shfl_down(s, o); ss += __shfl_down(ss, o); }
    const int wave = t >> 6, lane = t & 63;
    if (lane == 0) { red[wave][0] = s; red[wave][1] = ss; }
    __syncthreads();
    if (t == 0) {
        float S = 0.f, SS = 0.f;
        for (int w = 0; w < 4; ++w) { S += red[w][0]; SS += red[w][1]; }
        float m = S / width;
        float v = SS / width - m * m;
        red[0][0] = m; red[0][1] = rsqrtf(v + 1e-5f);
    }
    __syncthreads();
    const float m = red[0][0], rs = red[0][1];
    u16* op = out + row * width;
    for (int i = t; i < width; i += 256)
        op[i] = f2bf((buf[i] - m) * rs * g[i] + be[i]);
}

// ---------------------------------------------------------------------------
// MFMA GEMM (r15 structure): BK=32, dbuf global_load_lds, counted vmcnt.
// BM=BN=128, 256 thr. ACT: 0 none, 1 fast gelu, 2 relu.
// ---------------------------------------------------------------------------
template <int ACT, typename Tout>
__global__ __launch_bounds__(256) void mfma_gemm(
    const u16* __restrict__ A, const u16* __restrict__ Wt,
    const float* __restrict__ bias, Tout* __restrict__ C,
    int M, int N, int K)
{
    __shared__ __align__(16) u16 smem[16384];  // 32KB: 2x(A 4K u16 + B 4K u16); C-tile
    const int t    = threadIdx.x;
    const int m0   = blockIdx.x * 128;
    const int n0   = blockIdx.y * 128;
    const int lane = t & 63;
    const int wv   = t >> 6;
    const int wm   = (wv >> 1) * 64;
    const int wn   = (wv & 1) * 64;
    const int lr   = lane & 15;
    const int lks  = lane >> 4;

    const int nbase = wv * 64 + lane;
    const u16* aS[2]; const u16* bS[2];
#pragma unroll
    for (int j = 0; j < 2; ++j) {
        const int n   = j * 256 + nbase;
        const int row = n >> 2;
        const int src = (n & 3) ^ ((row >> 1) & 3);
        aS[j] = A  + (size_t)imin(m0 + row, M - 1) * K + src * 8;
        bS[j] = Wt + (size_t)imin(n0 + row, N - 1) * K + src * 8;
    }
    const int doff = (wv * 64) * 8;

    f32x4 acc[4][4] = {};
    const int nt = K >> 5;

#pragma unroll
    for (int j = 0; j < 2; ++j) {
        GLOAD16(aS[j], &smem[j * 2048 + doff]);
        GLOAD16(bS[j], &smem[4096 + j * 2048 + doff]);
    }
    if (nt > 1) {
#pragma unroll
        for (int j = 0; j < 2; ++j) {
            GLOAD16(aS[j] + 32, &smem[8192 + j * 2048 + doff]);
            GLOAD16(bS[j] + 32, &smem[8192 + 4096 + j * 2048 + doff]);
        }
    }

    for (int ti = 0; ti < nt; ++ti) {
        if (ti + 1 < nt) {
            asm volatile("s_waitcnt vmcnt(4)" ::: "memory");
        } else {
            asm volatile("s_waitcnt vmcnt(0)" ::: "memory");
        }
        __builtin_amdgcn_s_barrier();

        const int cb = (ti & 1) * 8192;
        const u16* Ab = &smem[cb];
        const u16* Bb = &smem[cb + 4096];
        s8bf af[4], bfr[4];
#pragma unroll
        for (int i = 0; i < 4; ++i) {
            const int ra = wm + i * 16 + lr;
            const int rb = wn + i * 16 + lr;
            af[i]  = *reinterpret_cast<const s8bf*>(
                &Ab[(size_t)((ra << 2) | (lks ^ ((ra >> 1) & 3))) * 8]);
            bfr[i] = *reinterpret_cast<const s8bf*>(
                &Bb[(size_t)((rb << 2) | (lks ^ ((rb >> 1) & 3))) * 8]);
        }
#pragma unroll
        for (int i = 0; i < 4; ++i)
#pragma unroll
            for (int j = 0; j < 4; ++j)
                acc[i][j] = __builtin_amdgcn_mfma_f32_16x16x32_bf16(af[i], bfr[j], acc[i][j], 0, 0, 0);

        __builtin_amdgcn_s_barrier();

        if (ti + 2 < nt) {
            const int k2 = (ti + 2) << 5;
#pragma unroll
            for (int j = 0; j < 2; ++j) {
                GLOAD16(aS[j] + k2, &smem[cb + j * 2048 + doff]);
                GLOAD16(bS[j] + k2, &smem[cb + 4096 + j * 2048 + doff]);
            }
        }
    }

    if constexpr (sizeof(Tout) == 2) {
        u16* Cs = smem;   // 16384 u16 = 128x128 bf16 tile
#pragma unroll
        for (int i = 0; i < 4; ++i)
#pragma unroll
            for (int j = 0; j < 4; ++j) {
                const int col = wn + j * 16 + lr;
                const float bb = bias[n0 + col];
#pragma unroll
                for (int r = 0; r < 4; ++r) {
                    const int row = wm + i * 16 + (lane >> 4) * 4 + r;
                    float v = acc[i][j][r] + bb;
                    if (ACT == 1) v = fast_gelu(v);
                    if (ACT == 2) v = v > 0.f ? v : 0.f;
                    const int xr = ((((row >> 2) & 3) ^ (row & 3)) << 4);
                    Cs[(row << 7) | (col ^ xr)] = f2bf(v);
                }
            }
        __syncthreads();
        u16* Cp = reinterpret_cast<u16*>(C);
#pragma unroll
        for (int it = 0; it < 8; ++it) {
            const int row = (t >> 4) + it * 16;
            const int gr  = m0 + row;
            const int q   = (t & 15) * 8;
            const int xr  = ((((row >> 2) & 3) ^ (row & 3)) << 4);
            s8bf v = *reinterpret_cast<const s8bf*>(&Cs[(row << 7) | (q ^ xr)]);
            if (gr < M)
                *reinterpret_cast<s8bf*>(Cp + (size_t)gr * N + n0 + q) = v;
        }
    } else {
#pragma unroll
        for (int i = 0; i < 4; ++i) {
            const int gr0 = m0 + wm + i * 16 + (lane >> 4) * 4;
#pragma unroll
            for (int j = 0; j < 4; ++j) {
                const int gc = n0 + wn + j * 16 + lr;
                if (gc >= N) continue;
                const float bb = bias[gc];
#pragma unroll
                for (int r = 0; r < 4; ++r) {
                    const int gr = gr0 + r;
                    if (gr >= M) continue;
                    float v = acc[i][j][r] + bb;
                    if (ACT == 1) v = fast_gelu(v);
                    if (ACT == 2) v = v > 0.f ? v : 0.f;
                    wr(C + (size_t)gr * N + gc, v);
                }
            }
        }
    }
}

// ---------------------------------------------------------------------------
// WIDE MFMA GEMM (r16 config, best measured): BM=128, BN=256, BK=32,
// 512 thr = 8 waves (2m x 4n), wave tile 64x64. LDS 64KB. Counted vmcnt(3).
// Requires N%256==0, K%32==0. bf16 out only. ACT: 0 none, 1 gelu, 2 relu.
// ---------------------------------------------------------------------------
template <int ACT>
__global__ __launch_bounds__(512) void mfma_gemm_wide(
    const u16* __restrict__ A, const u16* __restrict__ Wt,
    const float* __restrict__ bias, u16* __restrict__ C,
    int M, int N, int K)
{
    __shared__ __align__(16) u16 smem[32768];  // 64KB
    const int t    = threadIdx.x;
    const int m0   = blockIdx.x * 128;
    const int n0   = blockIdx.y * 256;
    const int lane = t & 63;
    const int wv   = t >> 6;              // 0..7
    const int wm   = (wv >> 2) * 64;      // 0,64
    const int wn   = (wv & 3) * 64;       // 0,64,128,192
    const int lr   = lane & 15;
    const int lks  = lane >> 4;

    const int nA = wv * 64 + lane;
    const int rA = nA >> 2, kA = (nA & 3) ^ ((rA >> 1) & 3);
    const u16* aS = A + (size_t)imin(m0 + rA, M - 1) * K + kA * 8;
    const u16* bS[2];
#pragma unroll
    for (int j = 0; j < 2; ++j) {
        const int n   = j * 512 + wv * 64 + lane;
        const int row = n >> 2;
        const int src = (n & 3) ^ ((row >> 1) & 3);
        bS[j] = Wt + (size_t)(n0 + row) * K + src * 8;
    }
    const int dA = (wv * 64) * 8;

    f32x4 acc[4][4] = {};
    const int nt = K >> 5;

    GLOAD16(aS, &smem[dA]);
#pragma unroll
    for (int j = 0; j < 2; ++j)
        GLOAD16(bS[j], &smem[4096 + (j * 512 + wv * 64) * 8]);
    if (nt > 1) {
        GLOAD16(aS + 32, &smem[12288 + dA]);
#pragma unroll
        for (int j = 0; j < 2; ++j)
            GLOAD16(bS[j] + 32, &smem[12288 + 4096 + (j * 512 + wv * 64) * 8]);
    }

    for (int ti = 0; ti < nt; ++ti) {
        if (ti + 1 < nt) {
            asm volatile("s_waitcnt vmcnt(3)" ::: "memory");
        } else {
            asm volatile("s_waitcnt vmcnt(0)" ::: "memory");
        }
        __builtin_amdgcn_s_barrier();

        const int cb = (ti & 1) * 12288;
        const u16* Ab = &smem[cb];
        const u16* Bb = &smem[cb + 4096];
        s8bf af[4], bfr[4];
#pragma unroll
        for (int i = 0; i < 4; ++i) {
            const int ra = wm + i * 16 + lr;
            const int rb = wn + i * 16 + lr;
            af[i]  = *reinterpret_cast<const s8bf*>(
                &Ab[(size_t)((ra << 2) | (lks ^ ((ra >> 1) & 3))) * 8]);
            bfr[i] = *reinterpret_cast<const s8bf*>(
                &Bb[(size_t)((rb << 2) | (lks ^ ((rb >> 1) & 3))) * 8]);
        }
#pragma unroll
        for (int i = 0; i < 4; ++i)
#pragma unroll
            for (int j = 0; j < 4; ++j)
                acc[i][j] = __builtin_amdgcn_mfma_f32_16x16x32_bf16(af[i], bfr[j], acc[i][j], 0, 0, 0);

        __builtin_amdgcn_s_barrier();

        if (ti + 2 < nt) {
            const int k2 = (ti + 2) << 5;
            GLOAD16(aS + k2, &smem[cb + dA]);
#pragma unroll
            for (int j = 0; j < 2; ++j)
                GLOAD16(bS[j] + k2, &smem[cb + 4096 + (j * 512 + wv * 64) * 8]);
        }
    }

    // ---- one-pass LDS-staged coalesced epilogue: C-tile 128x256 ----
    u16* Cs = smem;
#pragma unroll
    for (int i = 0; i < 4; ++i)
#pragma unroll
        for (int j = 0; j < 4; ++j) {
            const int col = wn + j * 16 + lr;            // 0..255
            const float bb = bias[n0 + col];
#pragma unroll
            for (int r = 0; r < 4; ++r) {
                const int row = wm + i * 16 + (lane >> 4) * 4 + r;   // 0..127
                float v = acc[i][j][r] + bb;
                if (ACT == 1) v = fast_gelu(v);
                if (ACT == 2) v = v > 0.f ? v : 0.f;
                const int xr = ((((row >> 2) & 3) ^ (row & 3)) << 4);
                Cs[(row << 8) | (col ^ xr)] = f2bf(v);
            }
        }
    __syncthreads();
#pragma unroll
    for (int it = 0; it < 8; ++it) {
        const int row = (t >> 5) + it * 16;              // 0..127
        const int gr  = m0 + row;
        const int q   = (t & 31) * 8;                    // 0..248
        const int xr  = ((((row >> 2) & 3) ^ (row & 3)) << 4);
        s8bf v = *reinterpret_cast<const s8bf*>(&Cs[(row << 8) | (q ^ xr)]);
        if (gr < M)
            *reinterpret_cast<s8bf*>(C + (size_t)gr * N + n0 + q) = v;
    }
}

// ---------------------------------------------------------------------------
// Bias concat for fused off+attn projection: b_cat[0:64)=b_off, [64:96)=b_attn
// ---------------------------------------------------------------------------
__global__ __launch_bounds__(128) void concat_bias_kernel(
    const float* __restrict__ b_off, const float* __restrict__ b_attn,
    float* __restrict__ b_cat)
{
    const int t = threadIdx.x;
    if (t < 64) b_cat[t] = b_off[t];
    else if (t < 96) b_cat[t] = b_attn[t - 64];
}

// ---------------------------------------------------------------------------
// Sampler v4 (r19): ILP restructure. Phase 2 uses 4 independent corner
// accumulators and a fully-unrolled p-loop issuing ALL 16 float4 gathers
// before the dependent fmacc chains consume them (r18 profile: VGPR=36 ->
// compiler kept p-loop rolled -> serial chain of 16 L2-latency waits).
// 4 chains of 4 instead of 1 chain of 16. 8 queries/block, 256 threads.
// ---------------------------------------------------------------------------
__global__ __launch_bounds__(256) void sample_kernel(
    const float* __restrict__ proj, const float* __restrict__ cpf,
    u16* __restrict__ out)
{
    __shared__ float4 sW[8][32];
    __shared__ int4   sT[8][32];

    const int blk = blockIdx.x;
    const int b   = blk / (NQ_ / 8);
    const int q0  = (blk % (NQ_ / 8)) * 8;
    const int t   = threadIdx.x;

    {
        const int qq = t >> 5, i = t & 31;
        const int h = i >> 2, p = i & 3;
        const size_t row = (size_t)b * NQ_ + q0 + qq;
        const float* pr = proj + row * 96;
        const float* lg = pr + 64 + h * 4;
        float l0 = lg[0], l1 = lg[1], l2 = lg[2], l3 = lg[3];
        float mx = fmaxf(fmaxf(l0, l1), fmaxf(l2, l3));
        float e0 = __expf(l0 - mx), e1 = __expf(l1 - mx);
        float e2 = __expf(l2 - mx), e3 = __expf(l3 - mx);
        float lp = (p == 0) ? l0 : (p == 1) ? l1 : (p == 2) ? l2 : l3;
        float aw = __expf(lp - mx) / (e0 + e1 + e2 + e3);
        float ox = pr[2 * i], oy = pr[2 * i + 1];
        float gx = 2.f * fast_sigmoid(ox) - 1.f;
        float gy = 2.f * fast_sigmoid(oy) - 1.f;
        float ix = ((gx + 1.f) * (float)GW_ - 1.f) * 0.5f;
        float iy = ((gy + 1.f) * (float)GW_ - 1.f) * 0.5f;
        float x0f = floorf(ix), y0f = floorf(iy);
        float wx1 = ix - x0f, wy1 = iy - y0f;
        float wx0 = 1.f - wx1, wy0 = 1.f - wy1;
        int xi = (int)x0f, yi = (int)y0f;
        bool vx0 = (xi >= 0) & (xi < GW_), vx1 = (xi + 1 >= 0) & (xi + 1 < GW_);
        bool vy0 = (yi >= 0) & (yi < GW_), vy1 = (yi + 1 >= 0) & (yi + 1 < GW_);
        float4 w;
        w.x = (vx0 & vy0) ? aw * wx0 * wy0 : 0.f;
        w.y = (vx1 & vy0) ? aw * wx1 * wy0 : 0.f;
        w.z = (vx0 & vy1) ? aw * wx0 * wy1 : 0.f;
        w.w = (vx1 & vy1) ? aw * wx1 * wy1 : 0.f;
        int cx0 = xi < 0 ? 0 : (xi > GW_ - 1 ? GW_ - 1 : xi);
        int cx1 = xi + 1 < 0 ? 0 : (xi + 1 > GW_ - 1 ? GW_ - 1 : xi + 1);
        int cy0 = yi < 0 ? 0 : (yi > GW_ - 1 ? GW_ - 1 : yi);
        int cy1 = yi + 1 < 0 ? 0 : (yi + 1 > GW_ - 1 ? GW_ - 1 : yi + 1);
        int4 tk;
        tk.x = cy0 * GW_ + cx0; tk.y = cy0 * GW_ + cx1;
        tk.z = cy1 * GW_ + cx0; tk.w = cy1 * GW_ + cx1;
        sW[qq][i] = w; sT[qq][i] = tk;
    }
    __syncthreads();

    const float4* vb4 = reinterpret_cast<const float4*>(cpf + (size_t)b * NT_ * D_ + D_);
    for (int idx = t; idx < 8 * 96; idx += 256) {   // 3 iterations
        const int qq = idx / 96, c4 = idx % 96, h = c4 / 12;
        // load all weights/tokens first (LDS broadcasts)
        int4   tk0 = sT[qq][h * 4 + 0], tk1 = sT[qq][h * 4 + 1];
        int4   tk2 = sT[qq][h * 4 + 2], tk3 = sT[qq][h * 4 + 3];
        float4 w0  = sW[qq][h * 4 + 0], w1  = sW[qq][h * 4 + 1];
        float4 w2  = sW[qq][h * 4 + 2], w3  = sW[qq][h * 4 + 3];
        // issue all 16 gathers (independent) before consuming
        float4 v00 = vb4[(size_t)tk0.x * 96 + c4], v01 = vb4[(size_t)tk0.y * 96 + c4];
        float4 v02 = vb4[(size_t)tk0.z * 96 + c4], v03 = vb4[(size_t)tk0.w * 96 + c4];
        float4 v10 = vb4[(size_t)tk1.x * 96 + c4], v11 = vb4[(size_t)tk1.y * 96 + c4];
        float4 v12 = vb4[(size_t)tk1.z * 96 + c4], v13 = vb4[(size_t)tk1.w * 96 + c4];
        float4 v20 = vb4[(size_t)tk2.x * 96 + c4], v21 = vb4[(size_t)tk2.y * 96 + c4];
        float4 v22 = vb4[(size_t)tk2.z * 96 + c4], v23 = vb4[(size_t)tk2.w * 96 + c4];
        float4 v30 = vb4[(size_t)tk3.x * 96 + c4], v31 = vb4[(size_t)tk3.y * 96 + c4];
        float4 v32 = vb4[(size_t)tk3.z * 96 + c4], v33 = vb4[(size_t)tk3.w * 96 + c4];
        // 4 independent accumulator chains (one per corner slot)
        float4 oA = make_float4(0.f, 0.f, 0.f, 0.f);
        float4 oB = make_float4(0.f, 0.f, 0.f, 0.f);
        float4 oC = make_float4(0.f, 0.f, 0.f, 0.f);
        float4 oD = make_float4(0.f, 0.f, 0.f, 0.f);
        fmacc4(oA, v00, w0.x); fmacc4(oB, v01, w0.y);
        fmacc4(oC, v02, w0.z); fmacc4(oD, v03, w0.w);
        fmacc4(oA, v10, w1.x); fmacc4(oB, v11, w1.y);
        fmacc4(oC, v12, w1.z); fmacc4(oD, v13, w1.w);
        fmacc4(oA, v20, w2.x); fmacc4(oB, v21, w2.y);
        fmacc4(oC, v22, w2.z); fmacc4(oD, v23, w2.w);
        fmacc4(oA, v30, w3.x); fmacc4(oB, v31, w3.y);
        fmacc4(oC, v32, w3.z); fmacc4(oD, v33, w3.w);
        float4 o;
        o.x = (oA.x + oB.x) + (oC.x + oD.x);
        o.y = (oA.y + oB.y) + (oC.y + oD.y);
        o.z = (oA.z + oB.z) + (oC.z + oD.z);
        o.w = (oA.w + oB.w) + (oC.w + oD.w);
        ushort4 pk;
        pk.x = f2bf(o.x); pk.y = f2bf(o.y); pk.z = f2bf(o.z); pk.w = f2bf(o.w);
        *reinterpret_cast<ushort4*>(&out[((size_t)b * NQ_ + q0 + qq) * D_ + c4 * 4]) = pk;
    }
}

// ---------------------------------------------------------------------------
// Gate reduce: gate[row] = sigmoid(dot(gh[row,0:96], Wg2) + bg2).
// ---------------------------------------------------------------------------
__global__ __launch_bounds__(256) void gate_reduce_kernel(
    const float* __restrict__ gh, const float* __restrict__ Wg2,
    const float* __restrict__ bg2, float* __restrict__ gate_out)
{
    const int wave = threadIdx.x >> 6, lane = threadIdx.x & 63;
    const size_t row = (size_t)blockIdx.x * 4 + wave;
    const float* h = gh + row * 96;
    float s = h[lane] * Wg2[lane];
    if (lane < 32) s += h[64 + lane] * Wg2[64 + lane];
#pragma unroll
    for (int o = 32; o > 0; o >>= 1) s += __shfl_down(s, o);
    if (lane == 0) gate_out[row] = 1.f / (1.f + expf(-(s + bg2[0])));
}

// ---------------------------------------------------------------------------
extern "C" void kernel_launch(void* const* d_in, const int* in_sizes, int n_in,
                              void* d_out, int out_size, void* d_ws, size_t ws_size,
                              hipStream_t stream)
{
    const float* visual = (const float*)d_in[0];
    const float* cut3r  = (const float*)d_in[1];
    const float* ln_v_g = (const float*)d_in[2];
    const float* ln_v_b = (const float*)d_in[3];
    const float* ln_c_g = (const float*)d_in[4];
    const float* ln_c_b = (const float*)d_in[5];
    const float* W_c1 = (const float*)d_in[6];
    const float* b_c1 = (const float*)d_in[7];
    const float* W_c2 = (const float*)d_in[8];
    const float* b_c2 = (const float*)d_in[9];
    const float* W_off = (const float*)d_in[10];
    const float* b_off = (const float*)d_in[11];
    const float* W_attn = (const float*)d_in[12];
    const float* b_attn = (const float*)d_in[13];
    const float* W_out = (const float*)d_in[14];
    const float* b_out = (const float*)d_in[15];
    const float* W_f1 = (const float*)d_in[16];
    const float* b_f1 = (const float*)d_in[17];
    const float* W_f2 = (const float*)d_in[18];
    const float* b_f2 = (const float*)d_in[19];
    const float* W_g1 = (const float*)d_in[20];
    const float* b_g1 = (const float*)d_in[21];
    const float* W_g2 = (const float*)d_in[22];
    const float* b_g2 = (const float*)d_in[23];
    const float* ln_o_g = (const float*)d_in[24];
    const float* ln_o_b = (const float*)d_in[25];

    // --- workspace layout (bytes); high-water ~86.8 MB (<=89.07 proven r3) ---
    char* ws = (char*)d_ws;
    u16*   vflat   = (u16*)(ws + 0);
    u16*   vn      = (u16*)(ws + 25165824);
    u16*   attn_out= (u16*)(ws + 25165824);
    u16*   chid    = (u16*)(ws + 50331648);
    u16*   dout    = (u16*)(ws + 50331648);
    u16*   ffn     = (u16*)(ws + 50331648);
    float* cpf     = (float*)(ws + 75497472);
    u16*   wt_f1b  = (u16*)(ws + 84467712);    // [1536][384]
    u16*   wt_f2b  = wt_f1b + 589824;          // [384][1536]

    // --- d_out as scratch (fully overwritten by final steps) ---
    float* dout_f   = (float*)d_out;
    u16*   cn       = (u16*)d_out;
    float* proj_buf = dout_f;
    float* b_cat    = dout_f + 3145728;
    float* gate_hid = dout_f;
    u16*   hidden   = (u16*)d_out;
    char*  wtp      = (char*)d_out + 25165824;
    u16* wt_c1   = (u16*)wtp;                  // [768][1024]
    u16* wt_c2   = wt_c1 + 786432;             // [384][768]
    u16* wt_out  = wt_c2 + 294912;             // [384][384]
    u16* wt_g1   = wt_out + 147456;            // [96][384]
    u16* wt_off  = wt_g1 + 36864;              // [64][384]  \ contiguous [96][384]
    u16* wt_attn = wt_off + 24576;             // [32][384]  /
    float* out_fused = dout_f;
    float* out_gate  = dout_f + (size_t)B_ * D_ * NQ_;

    // 0. ALL weight conversions in one launch + bias concat
    WtArgs wa;
    int cum = 0;
    auto fill = [&](int i, const float* src, u16* dst, int R, int C) {
        wa.d[i].src = src; wa.d[i].dst = dst; wa.d[i].R = R; wa.d[i].C = C;
        wa.d[i].start = cum; cum += (R >> 5) * (C >> 5);
    };
    fill(0, W_c1,  wt_c1,  1024, 768);
    fill(1, W_c2,  wt_c2,  768,  384);
    fill(2, W_out, wt_out, 384,  384);
    fill(3, W_g1,  wt_g1,  384,  96);
    fill(4, W_off, wt_off, 384,  64);
    fill(5, W_attn,wt_attn,384,  32);
    fill(6, W_f1,  wt_f1b, 384,  1536);
    fill(7, W_f2,  wt_f2b, 1536, 384);
    hipLaunchKernelGGL(wt_convert_kernel, dim3(cum), dim3(256), 0, stream, wa);
    hipLaunchKernelGGL(concat_bias_kernel, dim3(1), dim3(128), 0, stream, b_off, b_attn, b_cat);

    // 1. fused visual transpose + LN -> vflat (raw) + vn (normalized)
    hipLaunchKernelGGL(tr_ln_kernel, dim3(1024), dim3(256), 0, stream,
                       visual, ln_v_g, ln_v_b, vflat, vn);
    // 2. LN(cut3r f32) -> cn bf16 (d_out scratch)
    hipLaunchKernelGGL(ln_kernel, dim3(5840), dim3(256), 0, stream,
                       cut3r, ln_c_g, ln_c_b, cn, 1024);
    // 3. gelu(cn @ W_c1 + b_c1) -> chid bf16   [5840 x 768 x 1024]
    hipLaunchKernelGGL((mfma_gemm<1, u16>), dim3(46, 6), dim3(256), 0, stream,
                       cn, wt_c1, b_c1, chid, 5840, 768, 1024);
    // 4. chid @ W_c2 + b_c2 -> cpf f32 [B,730,384]   [5840 x 384 x 768]
    hipLaunchKernelGGL((mfma_gemm<0, float>), dim3(46, 3), dim3(256), 0, stream,
                       chid, wt_c2, b_c2, cpf, 5840, 384, 768);
    // 6. fused off+attn projection -> proj_buf f32 [32768 x 96 x 384] (cn dead)
    hipLaunchKernelGGL((mfma_gemm<0, float>), dim3(256, 1), dim3(256), 0, stream,
                       vn, wt_off, b_cat, proj_buf, 32768, 96, 384);
    // 7. sampler -> dout bf16 [B*Nq,384]  (cpf dead after)
    hipLaunchKernelGGL(sample_kernel, dim3(4096), dim3(256), 0, stream,
                       proj_buf, cpf, dout);
    // 8. dout @ W_out + b_out -> attn_out bf16   [32768 x 384 x 384] (vn dead)
    hipLaunchKernelGGL((mfma_gemm<0, u16>), dim3(256, 3), dim3(256), 0, stream,
                       dout, wt_out, b_out, attn_out, 32768, 384, 384);
    // 9. gate (proj_buf dead -> gate_hid reuses it)
    hipLaunchKernelGGL((mfma_gemm<2, float>), dim3(256, 1), dim3(256), 0, stream,
                       vflat, wt_g1, b_g1, gate_hid, 32768, 96, 384);
    hipLaunchKernelGGL(gate_reduce_kernel, dim3(8192), dim3(256), 0, stream,
                       gate_hid, W_g2, b_g2, out_gate);
    // 11. FFN in 2 row-chunks of 16384; f1 wide (r16 config)
    for (int c = 0; c < 2; ++c) {
        hipLaunchKernelGGL((mfma_gemm_wide<1>), dim3(128, 6), dim3(512), 0, stream,
                           attn_out + (size_t)c * 16384 * 384, wt_f1b, b_f1, hidden,
                           16384, 1536, 384);
        hipLaunchKernelGGL((mfma_gemm<0, u16>), dim3(128, 3), dim3(256), 0, stream,
                           hidden, wt_f2b, b_f2, ffn + (size_t)c * 16384 * 384,
                           16384, 384, 1536);
    }
    // 12. fused = LN(vflat + gate*ffn) written TRANSPOSED straight to d_out
    hipLaunchKernelGGL(fused_ln_tr_kernel, dim3(1024), dim3(256), 0, stream,
                       vflat, out_gate, ffn, ln_o_g, ln_o_b, out_fused);
}

// Round 20
// 327.310 us; speedup vs baseline: 1.0609x; 1.0609x over previous
//
#include <hip/hip_runtime.h>
#include <hip/hip_bf16.h>
#include <math.h>

// Problem constants
#define B_   8
#define D_   384
#define DC_  1024
#define NH_  8
#define NP_  4
#define DH_  48
#define NQ_  4096
#define NT_  730
#define NG_  729
#define GW_  27

typedef unsigned short u16;
typedef __attribute__((ext_vector_type(8))) short s8bf;   // 8 bf16 (4 VGPR)
typedef __attribute__((ext_vector_type(4))) float f32x4;  // MFMA accumulator

__device__ __forceinline__ float bf2f(u16 u) { return __uint_as_float(((unsigned)u) << 16); }
__device__ __forceinline__ u16 f2bf(float f) {
    __hip_bfloat16 h = __float2bfloat16(f);
    return *reinterpret_cast<u16*>(&h);
}
__device__ __forceinline__ float rd(const float* p) { return *p; }
__device__ __forceinline__ float rd(const u16* p)   { return bf2f(*p); }
__device__ __forceinline__ void  wr(float* p, float v) { *p = v; }
__device__ __forceinline__ void  wr(u16* p, float v)   { *p = f2bf(v); }
__device__ __forceinline__ void fmacc8(float* o, s8bf v, float w) {
#pragma unroll
    for (int k = 0; k < 8; ++k)
        o[k] = fmaf(bf2f((u16)v[k]), w, o[k]);
}
__device__ __forceinline__ int imin(int a, int b) { return a < b ? a : b; }
// tanh-form GELU (r11; dev vs exact erf-gelu ~3e-3, damped by gate~0.007)
__device__ __forceinline__ float fast_gelu(float x) {
    float z = 1.5957691216057308f * fmaf(0.044715f * x, x * x, x);
    return x / (1.f + __expf(-z));
}
__device__ __forceinline__ float fast_sigmoid(float x) {
    return 1.f / (1.f + __expf(-x));
}

// async 16B global->LDS (dest = wave-uniform base + lane*16)
#define GLOAD16(gp, lp) \
    __builtin_amdgcn_global_load_lds( \
        (const __attribute__((address_space(1))) void*)(gp), \
        (__attribute__((address_space(3))) void*)(lp), 16, 0, 0)

// ---------------------------------------------------------------------------
// Fused visual transpose + LayerNorm: visual f32 [B,384,4096] ->
// vflat bf16 [B,4096,384] (raw) AND vn bf16 (LN'd). One block = 32 queries.
// ---------------------------------------------------------------------------
__global__ __launch_bounds__(256) void tr_ln_kernel(
    const float* __restrict__ visual,
    const float* __restrict__ g, const float* __restrict__ be,
    u16* __restrict__ vflat, u16* __restrict__ vn)
{
    __shared__ float lds[D_][33];
    __shared__ float sM[32], sR[32];
    const int blk = blockIdx.x;
    const int b = blk >> 7, q0 = (blk & 127) << 5;
    const int t = threadIdx.x;
    const int tx = t & 31, ty = t >> 5;
    const float* vb = visual + (size_t)b * D_ * NQ_ + q0;
#pragma unroll
    for (int ct = 0; ct < 12; ++ct)
#pragma unroll
        for (int i = 0; i < 32; i += 8) {
            const int c = ct * 32 + ty + i;
            lds[c][tx] = vb[(size_t)c * NQ_ + tx];
        }
    __syncthreads();
    const int wv = t >> 6, lane = t & 63;
    for (int k = 0; k < 8; ++k) {
        const int q = wv * 8 + k;
        float s = 0.f, ss = 0.f;
#pragma unroll
        for (int e = 0; e < 6; ++e) {
            float v = lds[lane * 6 + e][q];
            s += v; ss += v * v;
        }
#pragma unroll
        for (int o = 32; o > 0; o >>= 1) { s += __shfl_down(s, o); ss += __shfl_down(ss, o); }
        if (lane == 0) {
            float m = s / (float)D_;
            sM[q] = m; sR[q] = rsqrtf(ss / (float)D_ - m * m + 1e-5f);
        }
    }
    __syncthreads();
    for (int idx = t; idx < 32 * D_; idx += 256) {
        const int q = idx / D_, c = idx % D_;
        const float raw = lds[c][q];
        const size_t row = (size_t)b * NQ_ + q0 + q;
        vflat[row * D_ + c] = f2bf(raw);
        vn[row * D_ + c]    = f2bf((raw - sM[q]) * sR[q] * g[c] + be[c]);
    }
}

// ---------------------------------------------------------------------------
// Fused output LN + transpose (r18): x = vflat + gate*ffn; LN(ln_o);
// write d_out f32 [B,384,4096] DIRECTLY (transposed).
// ---------------------------------------------------------------------------
__global__ __launch_bounds__(256) void fused_ln_tr_kernel(
    const u16* __restrict__ vflat, const float* __restrict__ gate,
    const u16* __restrict__ ffn,
    const float* __restrict__ g, const float* __restrict__ be,
    float* __restrict__ outT)
{
    __shared__ float buf[D_][33];
    __shared__ float sM[32], sR[32], sG[32];
    const int blk = blockIdx.x;
    const int b = blk >> 7, q0 = (blk & 127) << 5;
    const int t = threadIdx.x;
    const int tx = t & 31, ty = t >> 5;
    if (t < 32) sG[t] = gate[(size_t)b * NQ_ + q0 + t];
    __syncthreads();
    for (int idx = t; idx < 32 * D_; idx += 256) {
        const int q = idx / D_, c = idx % D_;
        const size_t row = (size_t)b * NQ_ + q0 + q;
        buf[c][q] = bf2f(vflat[row * D_ + c]) + sG[q] * bf2f(ffn[row * D_ + c]);
    }
    __syncthreads();
    const int wv = t >> 6, lane = t & 63;
    for (int k = 0; k < 8; ++k) {
        const int q = wv * 8 + k;
        float s = 0.f, ss = 0.f;
#pragma unroll
        for (int e = 0; e < 6; ++e) {
            float v = buf[lane * 6 + e][q];
            s += v; ss += v * v;
        }
#pragma unroll
        for (int o = 32; o > 0; o >>= 1) { s += __shfl_down(s, o); ss += __shfl_down(ss, o); }
        if (lane == 0) {
            float m = s / (float)D_;
            sM[q] = m; sR[q] = rsqrtf(ss / (float)D_ - m * m + 1e-5f);
        }
    }
    __syncthreads();
    float* ob = outT + (size_t)b * D_ * NQ_ + q0;
#pragma unroll
    for (int ct = 0; ct < 12; ++ct)
#pragma unroll
        for (int i = 0; i < 32; i += 8) {
            const int c = ct * 32 + ty + i;
            ob[(size_t)c * NQ_ + tx] = (buf[c][tx] - sM[tx]) * sR[tx] * g[c] + be[c];
        }
}

// ---------------------------------------------------------------------------
// Merged weight conversion: 8 weights f32[K,N] -> bf16[N,K] in ONE launch.
// ---------------------------------------------------------------------------
struct WtD { const float* src; u16* dst; int R; int C; int start; };
struct WtArgs { WtD d[8]; };

__global__ __launch_bounds__(256) void wt_convert_kernel(WtArgs a)
{
    __shared__ float tile[32][33];
    const int bt = blockIdx.x;
    int wi = 0;
#pragma unroll
    for (int k = 1; k < 8; ++k) if (bt >= a.d[k].start) wi = k;
    const float* src = a.d[wi].src;
    u16*         dst = a.d[wi].dst;
    const int R = a.d[wi].R, C = a.d[wi].C;
    const int local = bt - a.d[wi].start;
    const int tilesX = C >> 5;
    const int c0 = (local % tilesX) << 5;
    const int r0 = (local / tilesX) << 5;
    const int tx = threadIdx.x & 31, ty = threadIdx.x >> 5;
#pragma unroll
    for (int i = 0; i < 32; i += 8)
        tile[ty + i][tx] = src[(size_t)(r0 + ty + i) * C + c0 + tx];
    __syncthreads();
#pragma unroll
    for (int i = 0; i < 32; i += 8)
        dst[(size_t)(c0 + ty + i) * R + r0 + tx] = f2bf(tile[tx][ty + i]);
}

// ---------------------------------------------------------------------------
// Row LayerNorm (cut3r only): f32 in [rows][width] -> bf16 out. block 256.
// ---------------------------------------------------------------------------
__global__ __launch_bounds__(256) void ln_kernel(
    const float* __restrict__ x, const float* __restrict__ g, const float* __restrict__ be,
    u16* __restrict__ out, int width)
{
    __shared__ float buf[1024];
    __shared__ float red[4][2];
    const size_t row = blockIdx.x;
    const float* xr = x + row * width;
    const int t = threadIdx.x;
    float s = 0.f, ss = 0.f;
    for (int i = t; i < width; i += 256) {
        float v = xr[i]; buf[i] = v; s += v; ss += v * v;
    }
#pragma unroll
    for (int o = 32; o > 0; o >>= 1) { s += __shfl_down(s, o); ss += __shfl_down(ss, o); }
    const int wave = t >> 6, lane = t & 63;
    if (lane == 0) { red[wave][0] = s; red[wave][1] = ss; }
    __syncthreads();
    if (t == 0) {
        float S = 0.f, SS = 0.f;
        for (int w = 0; w < 4; ++w) { S += red[w][0]; SS += red[w][1]; }
        float m = S / width;
        float v = SS / width - m * m;
        red[0][0] = m; red[0][1] = rsqrtf(v + 1e-5f);
    }
    __syncthreads();
    const float m = red[0][0], rs = red[0][1];
    u16* op = out + row * width;
    for (int i = t; i < width; i += 256)
        op[i] = f2bf((buf[i] - m) * rs * g[i] + be[i]);
}

// ---------------------------------------------------------------------------
// MFMA GEMM (r15 structure): BK=32, dbuf global_load_lds, counted vmcnt.
// BM=BN=128, 256 thr. ACT: 0 none, 1 fast gelu, 2 relu.
// ---------------------------------------------------------------------------
template <int ACT, typename Tout>
__global__ __launch_bounds__(256) void mfma_gemm(
    const u16* __restrict__ A, const u16* __restrict__ Wt,
    const float* __restrict__ bias, Tout* __restrict__ C,
    int M, int N, int K)
{
    __shared__ __align__(16) u16 smem[16384];  // 32KB: 2x(A 4K u16 + B 4K u16); C-tile
    const int t    = threadIdx.x;
    const int m0   = blockIdx.x * 128;
    const int n0   = blockIdx.y * 128;
    const int lane = t & 63;
    const int wv   = t >> 6;
    const int wm   = (wv >> 1) * 64;
    const int wn   = (wv & 1) * 64;
    const int lr   = lane & 15;
    const int lks  = lane >> 4;

    const int nbase = wv * 64 + lane;
    const u16* aS[2]; const u16* bS[2];
#pragma unroll
    for (int j = 0; j < 2; ++j) {
        const int n   = j * 256 + nbase;
        const int row = n >> 2;
        const int src = (n & 3) ^ ((row >> 1) & 3);
        aS[j] = A  + (size_t)imin(m0 + row, M - 1) * K + src * 8;
        bS[j] = Wt + (size_t)imin(n0 + row, N - 1) * K + src * 8;
    }
    const int doff = (wv * 64) * 8;

    f32x4 acc[4][4] = {};
    const int nt = K >> 5;

#pragma unroll
    for (int j = 0; j < 2; ++j) {
        GLOAD16(aS[j], &smem[j * 2048 + doff]);
        GLOAD16(bS[j], &smem[4096 + j * 2048 + doff]);
    }
    if (nt > 1) {
#pragma unroll
        for (int j = 0; j < 2; ++j) {
            GLOAD16(aS[j] + 32, &smem[8192 + j * 2048 + doff]);
            GLOAD16(bS[j] + 32, &smem[8192 + 4096 + j * 2048 + doff]);
        }
    }

    for (int ti = 0; ti < nt; ++ti) {
        if (ti + 1 < nt) {
            asm volatile("s_waitcnt vmcnt(4)" ::: "memory");
        } else {
            asm volatile("s_waitcnt vmcnt(0)" ::: "memory");
        }
        __builtin_amdgcn_s_barrier();

        const int cb = (ti & 1) * 8192;
        const u16* Ab = &smem[cb];
        const u16* Bb = &smem[cb + 4096];
        s8bf af[4], bfr[4];
#pragma unroll
        for (int i = 0; i < 4; ++i) {
            const int ra = wm + i * 16 + lr;
            const int rb = wn + i * 16 + lr;
            af[i]  = *reinterpret_cast<const s8bf*>(
                &Ab[(size_t)((ra << 2) | (lks ^ ((ra >> 1) & 3))) * 8]);
            bfr[i] = *reinterpret_cast<const s8bf*>(
                &Bb[(size_t)((rb << 2) | (lks ^ ((rb >> 1) & 3))) * 8]);
        }
#pragma unroll
        for (int i = 0; i < 4; ++i)
#pragma unroll
            for (int j = 0; j < 4; ++j)
                acc[i][j] = __builtin_amdgcn_mfma_f32_16x16x32_bf16(af[i], bfr[j], acc[i][j], 0, 0, 0);

        __builtin_amdgcn_s_barrier();

        if (ti + 2 < nt) {
            const int k2 = (ti + 2) << 5;
#pragma unroll
            for (int j = 0; j < 2; ++j) {
                GLOAD16(aS[j] + k2, &smem[cb + j * 2048 + doff]);
                GLOAD16(bS[j] + k2, &smem[cb + 4096 + j * 2048 + doff]);
            }
        }
    }

    if constexpr (sizeof(Tout) == 2) {
        u16* Cs = smem;   // 16384 u16 = 128x128 bf16 tile
#pragma unroll
        for (int i = 0; i < 4; ++i)
#pragma unroll
            for (int j = 0; j < 4; ++j) {
                const int col = wn + j * 16 + lr;
                const float bb = bias[n0 + col];
#pragma unroll
                for (int r = 0; r < 4; ++r) {
                    const int row = wm + i * 16 + (lane >> 4) * 4 + r;
                    float v = acc[i][j][r] + bb;
                    if (ACT == 1) v = fast_gelu(v);
                    if (ACT == 2) v = v > 0.f ? v : 0.f;
                    const int xr = ((((row >> 2) & 3) ^ (row & 3)) << 4);
                    Cs[(row << 7) | (col ^ xr)] = f2bf(v);
                }
            }
        __syncthreads();
        u16* Cp = reinterpret_cast<u16*>(C);
#pragma unroll
        for (int it = 0; it < 8; ++it) {
            const int row = (t >> 4) + it * 16;
            const int gr  = m0 + row;
            const int q   = (t & 15) * 8;
            const int xr  = ((((row >> 2) & 3) ^ (row & 3)) << 4);
            s8bf v = *reinterpret_cast<const s8bf*>(&Cs[(row << 7) | (q ^ xr)]);
            if (gr < M)
                *reinterpret_cast<s8bf*>(Cp + (size_t)gr * N + n0 + q) = v;
        }
    } else {
#pragma unroll
        for (int i = 0; i < 4; ++i) {
            const int gr0 = m0 + wm + i * 16 + (lane >> 4) * 4;
#pragma unroll
            for (int j = 0; j < 4; ++j) {
                const int gc = n0 + wn + j * 16 + lr;
                if (gc >= N) continue;
                const float bb = bias[gc];
#pragma unroll
                for (int r = 0; r < 4; ++r) {
                    const int gr = gr0 + r;
                    if (gr >= M) continue;
                    float v = acc[i][j][r] + bb;
                    if (ACT == 1) v = fast_gelu(v);
                    if (ACT == 2) v = v > 0.f ? v : 0.f;
                    wr(C + (size_t)gr * N + gc, v);
                }
            }
        }
    }
}

// ---------------------------------------------------------------------------
// WIDE MFMA GEMM (r16 config, best measured): BM=128, BN=256, BK=32,
// 512 thr = 8 waves (2m x 4n), wave tile 64x64. LDS 64KB. Counted vmcnt(3).
// Requires N%256==0, K%32==0. bf16 out only. ACT: 0 none, 1 gelu, 2 relu.
// ---------------------------------------------------------------------------
template <int ACT>
__global__ __launch_bounds__(512) void mfma_gemm_wide(
    const u16* __restrict__ A, const u16* __restrict__ Wt,
    const float* __restrict__ bias, u16* __restrict__ C,
    int M, int N, int K)
{
    __shared__ __align__(16) u16 smem[32768];  // 64KB
    const int t    = threadIdx.x;
    const int m0   = blockIdx.x * 128;
    const int n0   = blockIdx.y * 256;
    const int lane = t & 63;
    const int wv   = t >> 6;              // 0..7
    const int wm   = (wv >> 2) * 64;      // 0,64
    const int wn   = (wv & 3) * 64;       // 0,64,128,192
    const int lr   = lane & 15;
    const int lks  = lane >> 4;

    const int nA = wv * 64 + lane;
    const int rA = nA >> 2, kA = (nA & 3) ^ ((rA >> 1) & 3);
    const u16* aS = A + (size_t)imin(m0 + rA, M - 1) * K + kA * 8;
    const u16* bS[2];
#pragma unroll
    for (int j = 0; j < 2; ++j) {
        const int n   = j * 512 + wv * 64 + lane;
        const int row = n >> 2;
        const int src = (n & 3) ^ ((row >> 1) & 3);
        bS[j] = Wt + (size_t)(n0 + row) * K + src * 8;
    }
    const int dA = (wv * 64) * 8;

    f32x4 acc[4][4] = {};
    const int nt = K >> 5;

    GLOAD16(aS, &smem[dA]);
#pragma unroll
    for (int j = 0; j < 2; ++j)
        GLOAD16(bS[j], &smem[4096 + (j * 512 + wv * 64) * 8]);
    if (nt > 1) {
        GLOAD16(aS + 32, &smem[12288 + dA]);
#pragma unroll
        for (int j = 0; j < 2; ++j)
            GLOAD16(bS[j] + 32, &smem[12288 + 4096 + (j * 512 + wv * 64) * 8]);
    }

    for (int ti = 0; ti < nt; ++ti) {
        if (ti + 1 < nt) {
            asm volatile("s_waitcnt vmcnt(3)" ::: "memory");
        } else {
            asm volatile("s_waitcnt vmcnt(0)" ::: "memory");
        }
        __builtin_amdgcn_s_barrier();

        const int cb = (ti & 1) * 12288;
        const u16* Ab = &smem[cb];
        const u16* Bb = &smem[cb + 4096];
        s8bf af[4], bfr[4];
#pragma unroll
        for (int i = 0; i < 4; ++i) {
            const int ra = wm + i * 16 + lr;
            const int rb = wn + i * 16 + lr;
            af[i]  = *reinterpret_cast<const s8bf*>(
                &Ab[(size_t)((ra << 2) | (lks ^ ((ra >> 1) & 3))) * 8]);
            bfr[i] = *reinterpret_cast<const s8bf*>(
                &Bb[(size_t)((rb << 2) | (lks ^ ((rb >> 1) & 3))) * 8]);
        }
#pragma unroll
        for (int i = 0; i < 4; ++i)
#pragma unroll
            for (int j = 0; j < 4; ++j)
                acc[i][j] = __builtin_amdgcn_mfma_f32_16x16x32_bf16(af[i], bfr[j], acc[i][j], 0, 0, 0);

        __builtin_amdgcn_s_barrier();

        if (ti + 2 < nt) {
            const int k2 = (ti + 2) << 5;
            GLOAD16(aS + k2, &smem[cb + dA]);
#pragma unroll
            for (int j = 0; j < 2; ++j)
                GLOAD16(bS[j] + k2, &smem[cb + 4096 + (j * 512 + wv * 64) * 8]);
        }
    }

    // ---- one-pass LDS-staged coalesced epilogue: C-tile 128x256 ----
    u16* Cs = smem;
#pragma unroll
    for (int i = 0; i < 4; ++i)
#pragma unroll
        for (int j = 0; j < 4; ++j) {
            const int col = wn + j * 16 + lr;            // 0..255
            const float bb = bias[n0 + col];
#pragma unroll
            for (int r = 0; r < 4; ++r) {
                const int row = wm + i * 16 + (lane >> 4) * 4 + r;   // 0..127
                float v = acc[i][j][r] + bb;
                if (ACT == 1) v = fast_gelu(v);
                if (ACT == 2) v = v > 0.f ? v : 0.f;
                const int xr = ((((row >> 2) & 3) ^ (row & 3)) << 4);
                Cs[(row << 8) | (col ^ xr)] = f2bf(v);
            }
        }
    __syncthreads();
#pragma unroll
    for (int it = 0; it < 8; ++it) {
        const int row = (t >> 5) + it * 16;              // 0..127
        const int gr  = m0 + row;
        const int q   = (t & 31) * 8;                    // 0..248
        const int xr  = ((((row >> 2) & 3) ^ (row & 3)) << 4);
        s8bf v = *reinterpret_cast<const s8bf*>(&Cs[(row << 8) | (q ^ xr)]);
        if (gr < M)
            *reinterpret_cast<s8bf*>(C + (size_t)gr * N + n0 + q) = v;
    }
}

// ---------------------------------------------------------------------------
// Bias concat for fused off+attn projection: b_cat[0:64)=b_off, [64:96)=b_attn
// ---------------------------------------------------------------------------
__global__ __launch_bounds__(128) void concat_bias_kernel(
    const float* __restrict__ b_off, const float* __restrict__ b_attn,
    float* __restrict__ b_cat)
{
    const int t = threadIdx.x;
    if (t < 64) b_cat[t] = b_off[t];
    else if (t < 96) b_cat[t] = b_attn[t - 64];
}

// ---------------------------------------------------------------------------
// Sampler v5 (r20): bf16 value grid. cpf16 bf16 [B,730,384]; gathers are
// ushort8 (16B = 8 channels) -> HALF the gather count AND half the L2 bytes
// vs f32 float4 (r19 profile: ~19 TB/s L2 ~ 55% ceiling). 16 queries/block,
// 256 threads, grid 2048. Unpack bf16->f32 is 1 VALU op/channel.
// ---------------------------------------------------------------------------
__global__ __launch_bounds__(256) void sample_kernel(
    const float* __restrict__ proj, const u16* __restrict__ cpf16,
    u16* __restrict__ out)
{
    __shared__ float4 sW[16][32];
    __shared__ int4   sT[16][32];

    const int blk = blockIdx.x;
    const int b   = blk / (NQ_ / 16);
    const int q0  = (blk % (NQ_ / 16)) * 16;
    const int t   = threadIdx.x;

    for (int it = t; it < 16 * 32; it += 256) {   // 2 iterations
        const int qq = it >> 5, i = it & 31;
        const int h = i >> 2, p = i & 3;
        const size_t row = (size_t)b * NQ_ + q0 + qq;
        const float* pr = proj + row * 96;
        const float* lg = pr + 64 + h * 4;
        float l0 = lg[0], l1 = lg[1], l2 = lg[2], l3 = lg[3];
        float mx = fmaxf(fmaxf(l0, l1), fmaxf(l2, l3));
        float e0 = __expf(l0 - mx), e1 = __expf(l1 - mx);
        float e2 = __expf(l2 - mx), e3 = __expf(l3 - mx);
        float lp = (p == 0) ? l0 : (p == 1) ? l1 : (p == 2) ? l2 : l3;
        float aw = __expf(lp - mx) / (e0 + e1 + e2 + e3);
        float ox = pr[2 * i], oy = pr[2 * i + 1];
        float gx = 2.f * fast_sigmoid(ox) - 1.f;
        float gy = 2.f * fast_sigmoid(oy) - 1.f;
        float ix = ((gx + 1.f) * (float)GW_ - 1.f) * 0.5f;
        float iy = ((gy + 1.f) * (float)GW_ - 1.f) * 0.5f;
        float x0f = floorf(ix), y0f = floorf(iy);
        float wx1 = ix - x0f, wy1 = iy - y0f;
        float wx0 = 1.f - wx1, wy0 = 1.f - wy1;
        int xi = (int)x0f, yi = (int)y0f;
        bool vx0 = (xi >= 0) & (xi < GW_), vx1 = (xi + 1 >= 0) & (xi + 1 < GW_);
        bool vy0 = (yi >= 0) & (yi < GW_), vy1 = (yi + 1 >= 0) & (yi + 1 < GW_);
        float4 w;
        w.x = (vx0 & vy0) ? aw * wx0 * wy0 : 0.f;
        w.y = (vx1 & vy0) ? aw * wx1 * wy0 : 0.f;
        w.z = (vx0 & vy1) ? aw * wx0 * wy1 : 0.f;
        w.w = (vx1 & vy1) ? aw * wx1 * wy1 : 0.f;
        int cx0 = xi < 0 ? 0 : (xi > GW_ - 1 ? GW_ - 1 : xi);
        int cx1 = xi + 1 < 0 ? 0 : (xi + 1 > GW_ - 1 ? GW_ - 1 : xi + 1);
        int cy0 = yi < 0 ? 0 : (yi > GW_ - 1 ? GW_ - 1 : yi);
        int cy1 = yi + 1 < 0 ? 0 : (yi + 1 > GW_ - 1 ? GW_ - 1 : yi + 1);
        int4 tk;
        tk.x = cy0 * GW_ + cx0; tk.y = cy0 * GW_ + cx1;
        tk.z = cy1 * GW_ + cx0; tk.w = cy1 * GW_ + cx1;
        sW[qq][i] = w; sT[qq][i] = tk;
    }
    __syncthreads();

    // value bf16 [b][1+p][c]: token row = 48 ushort8 chunks of 8 channels
    const s8bf* vb8 = reinterpret_cast<const s8bf*>(cpf16 + (size_t)b * NT_ * D_ + D_);
    for (int idx = t; idx < 16 * 48; idx += 256) {   // 3 iterations
        const int qq = idx / 48, c8 = idx % 48, h = c8 / 6;   // 6 chunks per head
        int4   tk0 = sT[qq][h * 4 + 0], tk1 = sT[qq][h * 4 + 1];
        int4   tk2 = sT[qq][h * 4 + 2], tk3 = sT[qq][h * 4 + 3];
        float4 w0  = sW[qq][h * 4 + 0], w1  = sW[qq][h * 4 + 1];
        float4 w2  = sW[qq][h * 4 + 2], w3  = sW[qq][h * 4 + 3];
        // issue all 16 ushort8 gathers before consuming
        s8bf v00 = vb8[(size_t)tk0.x * 48 + c8], v01 = vb8[(size_t)tk0.y * 48 + c8];
        s8bf v02 = vb8[(size_t)tk0.z * 48 + c8], v03 = vb8[(size_t)tk0.w * 48 + c8];
        s8bf v10 = vb8[(size_t)tk1.x * 48 + c8], v11 = vb8[(size_t)tk1.y * 48 + c8];
        s8bf v12 = vb8[(size_t)tk1.z * 48 + c8], v13 = vb8[(size_t)tk1.w * 48 + c8];
        s8bf v20 = vb8[(size_t)tk2.x * 48 + c8], v21 = vb8[(size_t)tk2.y * 48 + c8];
        s8bf v22 = vb8[(size_t)tk2.z * 48 + c8], v23 = vb8[(size_t)tk2.w * 48 + c8];
        s8bf v30 = vb8[(size_t)tk3.x * 48 + c8], v31 = vb8[(size_t)tk3.y * 48 + c8];
        s8bf v32 = vb8[(size_t)tk3.z * 48 + c8], v33 = vb8[(size_t)tk3.w * 48 + c8];
        float oA[8] = {0.f,0.f,0.f,0.f,0.f,0.f,0.f,0.f};
        float oB[8] = {0.f,0.f,0.f,0.f,0.f,0.f,0.f,0.f};
        fmacc8(oA, v00, w0.x); fmacc8(oB, v01, w0.y);
        fmacc8(oA, v02, w0.z); fmacc8(oB, v03, w0.w);
        fmacc8(oA, v10, w1.x); fmacc8(oB, v11, w1.y);
        fmacc8(oA, v12, w1.z); fmacc8(oB, v13, w1.w);
        fmacc8(oA, v20, w2.x); fmacc8(oB, v21, w2.y);
        fmacc8(oA, v22, w2.z); fmacc8(oB, v23, w2.w);
        fmacc8(oA, v30, w3.x); fmacc8(oB, v31, w3.y);
        fmacc8(oA, v32, w3.z); fmacc8(oB, v33, w3.w);
        s8bf pk;
#pragma unroll
        for (int k = 0; k < 8; ++k) pk[k] = (short)f2bf(oA[k] + oB[k]);
        *reinterpret_cast<s8bf*>(&out[((size_t)b * NQ_ + q0 + qq) * D_ + c8 * 8]) = pk;
    }
}

// ---------------------------------------------------------------------------
// Gate reduce: gate[row] = sigmoid(dot(gh[row,0:96], Wg2) + bg2).
// ---------------------------------------------------------------------------
__global__ __launch_bounds__(256) void gate_reduce_kernel(
    const float* __restrict__ gh, const float* __restrict__ Wg2,
    const float* __restrict__ bg2, float* __restrict__ gate_out)
{
    const int wave = threadIdx.x >> 6, lane = threadIdx.x & 63;
    const size_t row = (size_t)blockIdx.x * 4 + wave;
    const float* h = gh + row * 96;
    float s = h[lane] * Wg2[lane];
    if (lane < 32) s += h[64 + lane] * Wg2[64 + lane];
#pragma unroll
    for (int o = 32; o > 0; o >>= 1) s += __shfl_down(s, o);
    if (lane == 0) gate_out[row] = 1.f / (1.f + expf(-(s + bg2[0])));
}

// ---------------------------------------------------------------------------
extern "C" void kernel_launch(void* const* d_in, const int* in_sizes, int n_in,
                              void* d_out, int out_size, void* d_ws, size_t ws_size,
                              hipStream_t stream)
{
    const float* visual = (const float*)d_in[0];
    const float* cut3r  = (const float*)d_in[1];
    const float* ln_v_g = (const float*)d_in[2];
    const float* ln_v_b = (const float*)d_in[3];
    const float* ln_c_g = (const float*)d_in[4];
    const float* ln_c_b = (const float*)d_in[5];
    const float* W_c1 = (const float*)d_in[6];
    const float* b_c1 = (const float*)d_in[7];
    const float* W_c2 = (const float*)d_in[8];
    const float* b_c2 = (const float*)d_in[9];
    const float* W_off = (const float*)d_in[10];
    const float* b_off = (const float*)d_in[11];
    const float* W_attn = (const float*)d_in[12];
    const float* b_attn = (const float*)d_in[13];
    const float* W_out = (const float*)d_in[14];
    const float* b_out = (const float*)d_in[15];
    const float* W_f1 = (const float*)d_in[16];
    const float* b_f1 = (const float*)d_in[17];
    const float* W_f2 = (const float*)d_in[18];
    const float* b_f2 = (const float*)d_in[19];
    const float* W_g1 = (const float*)d_in[20];
    const float* b_g1 = (const float*)d_in[21];
    const float* W_g2 = (const float*)d_in[22];
    const float* b_g2 = (const float*)d_in[23];
    const float* ln_o_g = (const float*)d_in[24];
    const float* ln_o_b = (const float*)d_in[25];

    // --- workspace layout (bytes); high-water ~86.8 MB (<=89.07 proven r3) ---
    char* ws = (char*)d_ws;
    u16*   vflat   = (u16*)(ws + 0);
    u16*   vn      = (u16*)(ws + 25165824);
    u16*   attn_out= (u16*)(ws + 25165824);
    u16*   chid    = (u16*)(ws + 50331648);
    u16*   dout    = (u16*)(ws + 50331648);
    u16*   ffn     = (u16*)(ws + 50331648);
    u16*   cpf16   = (u16*)(ws + 75497472);    // bf16 [B,730,384] = 4.49 MB
    u16*   wt_f1b  = (u16*)(ws + 84467712);    // [1536][384]
    u16*   wt_f2b  = wt_f1b + 589824;          // [384][1536]

    // --- d_out as scratch (fully overwritten by final steps) ---
    float* dout_f   = (float*)d_out;
    u16*   cn       = (u16*)d_out;
    float* proj_buf = dout_f;
    float* b_cat    = dout_f + 3145728;
    float* gate_hid = dout_f;
    u16*   hidden   = (u16*)d_out;
    char*  wtp      = (char*)d_out + 25165824;
    u16* wt_c1   = (u16*)wtp;                  // [768][1024]
    u16* wt_c2   = wt_c1 + 786432;             // [384][768]
    u16* wt_out  = wt_c2 + 294912;             // [384][384]
    u16* wt_g1   = wt_out + 147456;            // [96][384]
    u16* wt_off  = wt_g1 + 36864;              // [64][384]  \ contiguous [96][384]
    u16* wt_attn = wt_off + 24576;             // [32][384]  /
    float* out_fused = dout_f;
    float* out_gate  = dout_f + (size_t)B_ * D_ * NQ_;

    // 0. ALL weight conversions in one launch + bias concat
    WtArgs wa;
    int cum = 0;
    auto fill = [&](int i, const float* src, u16* dst, int R, int C) {
        wa.d[i].src = src; wa.d[i].dst = dst; wa.d[i].R = R; wa.d[i].C = C;
        wa.d[i].start = cum; cum += (R >> 5) * (C >> 5);
    };
    fill(0, W_c1,  wt_c1,  1024, 768);
    fill(1, W_c2,  wt_c2,  768,  384);
    fill(2, W_out, wt_out, 384,  384);
    fill(3, W_g1,  wt_g1,  384,  96);
    fill(4, W_off, wt_off, 384,  64);
    fill(5, W_attn,wt_attn,384,  32);
    fill(6, W_f1,  wt_f1b, 384,  1536);
    fill(7, W_f2,  wt_f2b, 1536, 384);
    hipLaunchKernelGGL(wt_convert_kernel, dim3(cum), dim3(256), 0, stream, wa);
    hipLaunchKernelGGL(concat_bias_kernel, dim3(1), dim3(128), 0, stream, b_off, b_attn, b_cat);

    // 1. fused visual transpose + LN -> vflat (raw) + vn (normalized)
    hipLaunchKernelGGL(tr_ln_kernel, dim3(1024), dim3(256), 0, stream,
                       visual, ln_v_g, ln_v_b, vflat, vn);
    // 2. LN(cut3r f32) -> cn bf16 (d_out scratch)
    hipLaunchKernelGGL(ln_kernel, dim3(5840), dim3(256), 0, stream,
                       cut3r, ln_c_g, ln_c_b, cn, 1024);
    // 3. gelu(cn @ W_c1 + b_c1) -> chid bf16   [5840 x 768 x 1024]
    hipLaunchKernelGGL((mfma_gemm<1, u16>), dim3(46, 6), dim3(256), 0, stream,
                       cn, wt_c1, b_c1, chid, 5840, 768, 1024);
    // 4. chid @ W_c2 + b_c2 -> cpf16 bf16 [B,730,384]   [5840 x 384 x 768]
    hipLaunchKernelGGL((mfma_gemm<0, u16>), dim3(46, 3), dim3(256), 0, stream,
                       chid, wt_c2, b_c2, cpf16, 5840, 384, 768);
    // 6. fused off+attn projection -> proj_buf f32 [32768 x 96 x 384] (cn dead)
    hipLaunchKernelGGL((mfma_gemm<0, float>), dim3(256, 1), dim3(256), 0, stream,
                       vn, wt_off, b_cat, proj_buf, 32768, 96, 384);
    // 7. sampler (bf16 values, ushort8 gathers) -> dout bf16 [B*Nq,384]
    hipLaunchKernelGGL(sample_kernel, dim3(2048), dim3(256), 0, stream,
                       proj_buf, cpf16, dout);
    // 8. dout @ W_out + b_out -> attn_out bf16   [32768 x 384 x 384] (vn dead)
    hipLaunchKernelGGL((mfma_gemm<0, u16>), dim3(256, 3), dim3(256), 0, stream,
                       dout, wt_out, b_out, attn_out, 32768, 384, 384);
    // 9. gate (proj_buf dead -> gate_hid reuses it)
    hipLaunchKernelGGL((mfma_gemm<2, float>), dim3(256, 1), dim3(256), 0, stream,
                       vflat, wt_g1, b_g1, gate_hid, 32768, 96, 384);
    hipLaunchKernelGGL(gate_reduce_kernel, dim3(8192), dim3(256), 0, stream,
                       gate_hid, W_g2, b_g2, out_gate);
    // 11. FFN in 2 row-chunks of 16384; f1 wide (r16 config)
    for (int c = 0; c < 2; ++c) {
        hipLaunchKernelGGL((mfma_gemm_wide<1>), dim3(128, 6), dim3(512), 0, stream,
                           attn_out + (size_t)c * 16384 * 384, wt_f1b, b_f1, hidden,
                           16384, 1536, 384);
        hipLaunchKernelGGL((mfma_gemm<0, u16>), dim3(128, 3), dim3(256), 0, stream,
                           hidden, wt_f2b, b_f2, ffn + (size_t)c * 16384 * 384,
                           16384, 384, 1536);
    }
    // 12. fused = LN(vflat + gate*ffn) written TRANSPOSED straight to d_out
    hipLaunchKernelGGL(fused_ln_tr_kernel, dim3(1024), dim3(256), 0, stream,
                       vflat, out_gate, ffn, ln_o_g, ln_o_b, out_fused);
}

// Round 21
// 322.322 us; speedup vs baseline: 1.0773x; 1.0155x over previous
//
#include <hip/hip_runtime.h>
#include <hip/hip_bf16.h>
#include <math.h>

// Problem constants
#define B_   8
#define D_   384
#define DC_  1024
#define NH_  8
#define NP_  4
#define DH_  48
#define NQ_  4096
#define NT_  730
#define NG_  729
#define GW_  27

typedef unsigned short u16;
typedef __attribute__((ext_vector_type(8))) short s8bf;   // 8 bf16 (4 VGPR)
typedef __attribute__((ext_vector_type(4))) float f32x4;  // MFMA accumulator

__device__ __forceinline__ float bf2f(u16 u) { return __uint_as_float(((unsigned)u) << 16); }
__device__ __forceinline__ u16 f2bf(float f) {
    __hip_bfloat16 h = __float2bfloat16(f);
    return *reinterpret_cast<u16*>(&h);
}
__device__ __forceinline__ float rd(const float* p) { return *p; }
__device__ __forceinline__ float rd(const u16* p)   { return bf2f(*p); }
__device__ __forceinline__ void  wr(float* p, float v) { *p = v; }
__device__ __forceinline__ void  wr(u16* p, float v)   { *p = f2bf(v); }
__device__ __forceinline__ void fmacc8(float* o, s8bf v, float w) {
#pragma unroll
    for (int k = 0; k < 8; ++k)
        o[k] = fmaf(bf2f((u16)v[k]), w, o[k]);
}
__device__ __forceinline__ int imin(int a, int b) { return a < b ? a : b; }
// tanh-form GELU (r11; dev vs exact erf-gelu ~3e-3, damped by gate~0.007)
__device__ __forceinline__ float fast_gelu(float x) {
    float z = 1.5957691216057308f * fmaf(0.044715f * x, x * x, x);
    return x / (1.f + __expf(-z));
}
__device__ __forceinline__ float fast_sigmoid(float x) {
    return 1.f / (1.f + __expf(-x));
}

// async 16B global->LDS (dest = wave-uniform base + lane*16)
#define GLOAD16(gp, lp) \
    __builtin_amdgcn_global_load_lds( \
        (const __attribute__((address_space(1))) void*)(gp), \
        (__attribute__((address_space(3))) void*)(lp), 16, 0, 0)

// ---------------------------------------------------------------------------
// Fused visual transpose + LayerNorm: visual f32 [B,384,4096] ->
// vflat bf16 [B,4096,384] (raw) AND vn bf16 (LN'd). One block = 32 queries.
// ---------------------------------------------------------------------------
__global__ __launch_bounds__(256) void tr_ln_kernel(
    const float* __restrict__ visual,
    const float* __restrict__ g, const float* __restrict__ be,
    u16* __restrict__ vflat, u16* __restrict__ vn)
{
    __shared__ float lds[D_][33];
    __shared__ float sM[32], sR[32];
    const int blk = blockIdx.x;
    const int b = blk >> 7, q0 = (blk & 127) << 5;
    const int t = threadIdx.x;
    const int tx = t & 31, ty = t >> 5;
    const float* vb = visual + (size_t)b * D_ * NQ_ + q0;
#pragma unroll
    for (int ct = 0; ct < 12; ++ct)
#pragma unroll
        for (int i = 0; i < 32; i += 8) {
            const int c = ct * 32 + ty + i;
            lds[c][tx] = vb[(size_t)c * NQ_ + tx];
        }
    __syncthreads();
    const int wv = t >> 6, lane = t & 63;
    for (int k = 0; k < 8; ++k) {
        const int q = wv * 8 + k;
        float s = 0.f, ss = 0.f;
#pragma unroll
        for (int e = 0; e < 6; ++e) {
            float v = lds[lane * 6 + e][q];
            s += v; ss += v * v;
        }
#pragma unroll
        for (int o = 32; o > 0; o >>= 1) { s += __shfl_down(s, o); ss += __shfl_down(ss, o); }
        if (lane == 0) {
            float m = s / (float)D_;
            sM[q] = m; sR[q] = rsqrtf(ss / (float)D_ - m * m + 1e-5f);
        }
    }
    __syncthreads();
    for (int idx = t; idx < 32 * D_; idx += 256) {
        const int q = idx / D_, c = idx % D_;
        const float raw = lds[c][q];
        const size_t row = (size_t)b * NQ_ + q0 + q;
        vflat[row * D_ + c] = f2bf(raw);
        vn[row * D_ + c]    = f2bf((raw - sM[q]) * sR[q] * g[c] + be[c]);
    }
}

// ---------------------------------------------------------------------------
// Fused output LN + transpose (r18): x = vflat + gate*ffn; LN(ln_o);
// write d_out f32 [B,384,4096] DIRECTLY (transposed).
// ---------------------------------------------------------------------------
__global__ __launch_bounds__(256) void fused_ln_tr_kernel(
    const u16* __restrict__ vflat, const float* __restrict__ gate,
    const u16* __restrict__ ffn,
    const float* __restrict__ g, const float* __restrict__ be,
    float* __restrict__ outT)
{
    __shared__ float buf[D_][33];
    __shared__ float sM[32], sR[32], sG[32];
    const int blk = blockIdx.x;
    const int b = blk >> 7, q0 = (blk & 127) << 5;
    const int t = threadIdx.x;
    const int tx = t & 31, ty = t >> 5;
    if (t < 32) sG[t] = gate[(size_t)b * NQ_ + q0 + t];
    __syncthreads();
    for (int idx = t; idx < 32 * D_; idx += 256) {
        const int q = idx / D_, c = idx % D_;
        const size_t row = (size_t)b * NQ_ + q0 + q;
        buf[c][q] = bf2f(vflat[row * D_ + c]) + sG[q] * bf2f(ffn[row * D_ + c]);
    }
    __syncthreads();
    const int wv = t >> 6, lane = t & 63;
    for (int k = 0; k < 8; ++k) {
        const int q = wv * 8 + k;
        float s = 0.f, ss = 0.f;
#pragma unroll
        for (int e = 0; e < 6; ++e) {
            float v = buf[lane * 6 + e][q];
            s += v; ss += v * v;
        }
#pragma unroll
        for (int o = 32; o > 0; o >>= 1) { s += __shfl_down(s, o); ss += __shfl_down(ss, o); }
        if (lane == 0) {
            float m = s / (float)D_;
            sM[q] = m; sR[q] = rsqrtf(ss / (float)D_ - m * m + 1e-5f);
        }
    }
    __syncthreads();
    float* ob = outT + (size_t)b * D_ * NQ_ + q0;
#pragma unroll
    for (int ct = 0; ct < 12; ++ct)
#pragma unroll
        for (int i = 0; i < 32; i += 8) {
            const int c = ct * 32 + ty + i;
            ob[(size_t)c * NQ_ + tx] = (buf[c][tx] - sM[tx]) * sR[tx] * g[c] + be[c];
        }
}

// ---------------------------------------------------------------------------
// Merged weight conversion: 8 weights f32[K,N] -> bf16[N,K] in ONE launch.
// ---------------------------------------------------------------------------
struct WtD { const float* src; u16* dst; int R; int C; int start; };
struct WtArgs { WtD d[8]; };

__global__ __launch_bounds__(256) void wt_convert_kernel(WtArgs a)
{
    __shared__ float tile[32][33];
    const int bt = blockIdx.x;
    int wi = 0;
#pragma unroll
    for (int k = 1; k < 8; ++k) if (bt >= a.d[k].start) wi = k;
    const float* src = a.d[wi].src;
    u16*         dst = a.d[wi].dst;
    const int R = a.d[wi].R, C = a.d[wi].C;
    const int local = bt - a.d[wi].start;
    const int tilesX = C >> 5;
    const int c0 = (local % tilesX) << 5;
    const int r0 = (local / tilesX) << 5;
    const int tx = threadIdx.x & 31, ty = threadIdx.x >> 5;
#pragma unroll
    for (int i = 0; i < 32; i += 8)
        tile[ty + i][tx] = src[(size_t)(r0 + ty + i) * C + c0 + tx];
    __syncthreads();
#pragma unroll
    for (int i = 0; i < 32; i += 8)
        dst[(size_t)(c0 + ty + i) * R + r0 + tx] = f2bf(tile[tx][ty + i]);
}

// ---------------------------------------------------------------------------
// Row LayerNorm (cut3r only): f32 in [rows][width] -> bf16 out. block 256.
// ---------------------------------------------------------------------------
__global__ __launch_bounds__(256) void ln_kernel(
    const float* __restrict__ x, const float* __restrict__ g, const float* __restrict__ be,
    u16* __restrict__ out, int width)
{
    __shared__ float buf[1024];
    __shared__ float red[4][2];
    const size_t row = blockIdx.x;
    const float* xr = x + row * width;
    const int t = threadIdx.x;
    float s = 0.f, ss = 0.f;
    for (int i = t; i < width; i += 256) {
        float v = xr[i]; buf[i] = v; s += v; ss += v * v;
    }
#pragma unroll
    for (int o = 32; o > 0; o >>= 1) { s += __shfl_down(s, o); ss += __shfl_down(ss, o); }
    const int wave = t >> 6, lane = t & 63;
    if (lane == 0) { red[wave][0] = s; red[wave][1] = ss; }
    __syncthreads();
    if (t == 0) {
        float S = 0.f, SS = 0.f;
        for (int w = 0; w < 4; ++w) { S += red[w][0]; SS += red[w][1]; }
        float m = S / width;
        float v = SS / width - m * m;
        red[0][0] = m; red[0][1] = rsqrtf(v + 1e-5f);
    }
    __syncthreads();
    const float m = red[0][0], rs = red[0][1];
    u16* op = out + row * width;
    for (int i = t; i < width; i += 256)
        op[i] = f2bf((buf[i] - m) * rs * g[i] + be[i]);
}

// ---------------------------------------------------------------------------
// MFMA GEMM (r15 structure): BK=32, dbuf global_load_lds, counted vmcnt.
// BM=BN=128, 256 thr. ACT: 0 none, 1 fast gelu, 2 relu.
// ---------------------------------------------------------------------------
template <int ACT, typename Tout>
__global__ __launch_bounds__(256) void mfma_gemm(
    const u16* __restrict__ A, const u16* __restrict__ Wt,
    const float* __restrict__ bias, Tout* __restrict__ C,
    int M, int N, int K)
{
    __shared__ __align__(16) u16 smem[16384];  // 32KB: 2x(A 4K u16 + B 4K u16); C-tile
    const int t    = threadIdx.x;
    const int m0   = blockIdx.x * 128;
    const int n0   = blockIdx.y * 128;
    const int lane = t & 63;
    const int wv   = t >> 6;
    const int wm   = (wv >> 1) * 64;
    const int wn   = (wv & 1) * 64;
    const int lr   = lane & 15;
    const int lks  = lane >> 4;

    const int nbase = wv * 64 + lane;
    const u16* aS[2]; const u16* bS[2];
#pragma unroll
    for (int j = 0; j < 2; ++j) {
        const int n   = j * 256 + nbase;
        const int row = n >> 2;
        const int src = (n & 3) ^ ((row >> 1) & 3);
        aS[j] = A  + (size_t)imin(m0 + row, M - 1) * K + src * 8;
        bS[j] = Wt + (size_t)imin(n0 + row, N - 1) * K + src * 8;
    }
    const int doff = (wv * 64) * 8;

    f32x4 acc[4][4] = {};
    const int nt = K >> 5;

#pragma unroll
    for (int j = 0; j < 2; ++j) {
        GLOAD16(aS[j], &smem[j * 2048 + doff]);
        GLOAD16(bS[j], &smem[4096 + j * 2048 + doff]);
    }
    if (nt > 1) {
#pragma unroll
        for (int j = 0; j < 2; ++j) {
            GLOAD16(aS[j] + 32, &smem[8192 + j * 2048 + doff]);
            GLOAD16(bS[j] + 32, &smem[8192 + 4096 + j * 2048 + doff]);
        }
    }

    for (int ti = 0; ti < nt; ++ti) {
        if (ti + 1 < nt) {
            asm volatile("s_waitcnt vmcnt(4)" ::: "memory");
        } else {
            asm volatile("s_waitcnt vmcnt(0)" ::: "memory");
        }
        __builtin_amdgcn_s_barrier();

        const int cb = (ti & 1) * 8192;
        const u16* Ab = &smem[cb];
        const u16* Bb = &smem[cb + 4096];
        s8bf af[4], bfr[4];
#pragma unroll
        for (int i = 0; i < 4; ++i) {
            const int ra = wm + i * 16 + lr;
            const int rb = wn + i * 16 + lr;
            af[i]  = *reinterpret_cast<const s8bf*>(
                &Ab[(size_t)((ra << 2) | (lks ^ ((ra >> 1) & 3))) * 8]);
            bfr[i] = *reinterpret_cast<const s8bf*>(
                &Bb[(size_t)((rb << 2) | (lks ^ ((rb >> 1) & 3))) * 8]);
        }
#pragma unroll
        for (int i = 0; i < 4; ++i)
#pragma unroll
            for (int j = 0; j < 4; ++j)
                acc[i][j] = __builtin_amdgcn_mfma_f32_16x16x32_bf16(af[i], bfr[j], acc[i][j], 0, 0, 0);

        __builtin_amdgcn_s_barrier();

        if (ti + 2 < nt) {
            const int k2 = (ti + 2) << 5;
#pragma unroll
            for (int j = 0; j < 2; ++j) {
                GLOAD16(aS[j] + k2, &smem[cb + j * 2048 + doff]);
                GLOAD16(bS[j] + k2, &smem[cb + 4096 + j * 2048 + doff]);
            }
        }
    }

    if constexpr (sizeof(Tout) == 2) {
        u16* Cs = smem;   // 16384 u16 = 128x128 bf16 tile
#pragma unroll
        for (int i = 0; i < 4; ++i)
#pragma unroll
            for (int j = 0; j < 4; ++j) {
                const int col = wn + j * 16 + lr;
                const float bb = bias[n0 + col];
#pragma unroll
                for (int r = 0; r < 4; ++r) {
                    const int row = wm + i * 16 + (lane >> 4) * 4 + r;
                    float v = acc[i][j][r] + bb;
                    if (ACT == 1) v = fast_gelu(v);
                    if (ACT == 2) v = v > 0.f ? v : 0.f;
                    const int xr = ((((row >> 2) & 3) ^ (row & 3)) << 4);
                    Cs[(row << 7) | (col ^ xr)] = f2bf(v);
                }
            }
        __syncthreads();
        u16* Cp = reinterpret_cast<u16*>(C);
#pragma unroll
        for (int it = 0; it < 8; ++it) {
            const int row = (t >> 4) + it * 16;
            const int gr  = m0 + row;
            const int q   = (t & 15) * 8;
            const int xr  = ((((row >> 2) & 3) ^ (row & 3)) << 4);
            s8bf v = *reinterpret_cast<const s8bf*>(&Cs[(row << 7) | (q ^ xr)]);
            if (gr < M)
                *reinterpret_cast<s8bf*>(Cp + (size_t)gr * N + n0 + q) = v;
        }
    } else {
#pragma unroll
        for (int i = 0; i < 4; ++i) {
            const int gr0 = m0 + wm + i * 16 + (lane >> 4) * 4;
#pragma unroll
            for (int j = 0; j < 4; ++j) {
                const int gc = n0 + wn + j * 16 + lr;
                if (gc >= N) continue;
                const float bb = bias[gc];
#pragma unroll
                for (int r = 0; r < 4; ++r) {
                    const int gr = gr0 + r;
                    if (gr >= M) continue;
                    float v = acc[i][j][r] + bb;
                    if (ACT == 1) v = fast_gelu(v);
                    if (ACT == 2) v = v > 0.f ? v : 0.f;
                    wr(C + (size_t)gr * N + gc, v);
                }
            }
        }
    }
}

// ---------------------------------------------------------------------------
// MFMA GEMM K64 (r21): BK=64, dbuf global_load_lds, counted vmcnt(8).
// BM=BN=128, 256 thr. Halves barrier/wait events vs BK=32 (f2: 48->24 iters).
// LDS 64KB: 2 buf x (A 16KB + B 16KB). 8 DMAs/wave/tile. 8-slot swizzle
// (r12-verified, 0 conflicts): granule (row, sl) holds source k-slot
// sl ^ ((row>>1)&7); reads use same map. Accumulation order identical to
// BK=32 kernel (same 32-K MFMA sequence) -> bitwise-equal output.
// bf16 out only. Requires M? clamped; N%128==0 here; K%64==0.
// ---------------------------------------------------------------------------
template <int ACT>
__global__ __launch_bounds__(256) void mfma_gemm_k64(
    const u16* __restrict__ A, const u16* __restrict__ Wt,
    const float* __restrict__ bias, u16* __restrict__ C,
    int M, int N, int K)
{
    __shared__ __align__(16) u16 smem[32768];  // 64KB: 2 buf x (A 8K u16 + B 8K u16)
    const int t    = threadIdx.x;
    const int m0   = blockIdx.x * 128;
    const int n0   = blockIdx.y * 128;
    const int lane = t & 63;
    const int wv   = t >> 6;
    const int wm   = (wv >> 1) * 64;
    const int wn   = (wv & 1) * 64;
    const int lr   = lane & 15;
    const int lks  = lane >> 4;

    // staging: per matrix, issue j covers granule n = j*256 + wv*64 + lane
    // (1024 granules = 128 rows x 8 slots); granule n: row = n>>3, sl = n&7,
    // source k-slot = sl ^ ((row>>1)&7)
    const u16* aS[4]; const u16* bS[4];
#pragma unroll
    for (int j = 0; j < 4; ++j) {
        const int n   = j * 256 + wv * 64 + lane;
        const int row = n >> 3;
        const int src = (n & 7) ^ ((row >> 1) & 7);
        aS[j] = A  + (size_t)imin(m0 + row, M - 1) * K + src * 8;
        bS[j] = Wt + (size_t)imin(n0 + row, N - 1) * K + src * 8;
    }
    const int doff = (wv * 64) * 8;

    f32x4 acc[4][4] = {};
    const int nt = K >> 6;

    // prologue: T0 -> buf0, T1 -> buf1 (16 DMAs/wave outstanding)
#pragma unroll
    for (int j = 0; j < 4; ++j) {
        GLOAD16(aS[j], &smem[j * 2048 + doff]);
        GLOAD16(bS[j], &smem[8192 + j * 2048 + doff]);
    }
    if (nt > 1) {
#pragma unroll
        for (int j = 0; j < 4; ++j) {
            GLOAD16(aS[j] + 64, &smem[16384 + j * 2048 + doff]);
            GLOAD16(bS[j] + 64, &smem[16384 + 8192 + j * 2048 + doff]);
        }
    }

    for (int ti = 0; ti < nt; ++ti) {
        // oldest 8 = tile ti complete (in-order vmcnt); drain fully on last
        if (ti + 1 < nt) {
            asm volatile("s_waitcnt vmcnt(8)" ::: "memory");
        } else {
            asm volatile("s_waitcnt vmcnt(0)" ::: "memory");
        }
        __builtin_amdgcn_s_barrier();

        const int cb = (ti & 1) * 16384;
        const u16* Ab = &smem[cb];
        const u16* Bb = &smem[cb + 8192];
#pragma unroll
        for (int sub = 0; sub < 2; ++sub) {
            const int srcslot = lks + (sub << 2);
            s8bf af[4], bfr[4];
#pragma unroll
            for (int i = 0; i < 4; ++i) {
                const int ra = wm + i * 16 + lr;
                const int rb = wn + i * 16 + lr;
                af[i]  = *reinterpret_cast<const s8bf*>(
                    &Ab[(size_t)((ra << 3) | (srcslot ^ ((ra >> 1) & 7))) * 8]);
                bfr[i] = *reinterpret_cast<const s8bf*>(
                    &Bb[(size_t)((rb << 3) | (srcslot ^ ((rb >> 1) & 7))) * 8]);
            }
#pragma unroll
            for (int i = 0; i < 4; ++i)
#pragma unroll
                for (int j = 0; j < 4; ++j)
                    acc[i][j] = __builtin_amdgcn_mfma_f32_16x16x32_bf16(af[i], bfr[j], acc[i][j], 0, 0, 0);
        }

        __builtin_amdgcn_s_barrier();   // all waves done reading buf[ti&1]

        if (ti + 2 < nt) {
            const int k2 = (ti + 2) << 6;
#pragma unroll
            for (int j = 0; j < 4; ++j) {
                GLOAD16(aS[j] + k2, &smem[cb + j * 2048 + doff]);
                GLOAD16(bS[j] + k2, &smem[cb + 8192 + j * 2048 + doff]);
            }
        }
    }

    // ---- LDS-staged coalesced epilogue (r13): C-tile 128x128 in smem ----
    u16* Cs = smem;
#pragma unroll
    for (int i = 0; i < 4; ++i)
#pragma unroll
        for (int j = 0; j < 4; ++j) {
            const int col = wn + j * 16 + lr;
            const float bb = bias[n0 + col];
#pragma unroll
            for (int r = 0; r < 4; ++r) {
                const int row = wm + i * 16 + (lane >> 4) * 4 + r;
                float v = acc[i][j][r] + bb;
                if (ACT == 1) v = fast_gelu(v);
                if (ACT == 2) v = v > 0.f ? v : 0.f;
                const int xr = ((((row >> 2) & 3) ^ (row & 3)) << 4);
                Cs[(row << 7) | (col ^ xr)] = f2bf(v);
            }
        }
    __syncthreads();
#pragma unroll
    for (int it = 0; it < 8; ++it) {
        const int row = (t >> 4) + it * 16;
        const int gr  = m0 + row;
        const int q   = (t & 15) * 8;
        const int xr  = ((((row >> 2) & 3) ^ (row & 3)) << 4);
        s8bf v = *reinterpret_cast<const s8bf*>(&Cs[(row << 7) | (q ^ xr)]);
        if (gr < M)
            *reinterpret_cast<s8bf*>(C + (size_t)gr * N + n0 + q) = v;
    }
}

// ---------------------------------------------------------------------------
// WIDE MFMA GEMM (r16 config, best measured): BM=128, BN=256, BK=32,
// 512 thr = 8 waves (2m x 4n), wave tile 64x64. LDS 64KB. Counted vmcnt(3).
// Requires N%256==0, K%32==0. bf16 out only. ACT: 0 none, 1 gelu, 2 relu.
// ---------------------------------------------------------------------------
template <int ACT>
__global__ __launch_bounds__(512) void mfma_gemm_wide(
    const u16* __restrict__ A, const u16* __restrict__ Wt,
    const float* __restrict__ bias, u16* __restrict__ C,
    int M, int N, int K)
{
    __shared__ __align__(16) u16 smem[32768];  // 64KB
    const int t    = threadIdx.x;
    const int m0   = blockIdx.x * 128;
    const int n0   = blockIdx.y * 256;
    const int lane = t & 63;
    const int wv   = t >> 6;              // 0..7
    const int wm   = (wv >> 2) * 64;      // 0,64
    const int wn   = (wv & 3) * 64;       // 0,64,128,192
    const int lr   = lane & 15;
    const int lks  = lane >> 4;

    const int nA = wv * 64 + lane;
    const int rA = nA >> 2, kA = (nA & 3) ^ ((rA >> 1) & 3);
    const u16* aS = A + (size_t)imin(m0 + rA, M - 1) * K + kA * 8;
    const u16* bS[2];
#pragma unroll
    for (int j = 0; j < 2; ++j) {
        const int n   = j * 512 + wv * 64 + lane;
        const int row = n >> 2;
        const int src = (n & 3) ^ ((row >> 1) & 3);
        bS[j] = Wt + (size_t)(n0 + row) * K + src * 8;
    }
    const int dA = (wv * 64) * 8;

    f32x4 acc[4][4] = {};
    const int nt = K >> 5;

    GLOAD16(aS, &smem[dA]);
#pragma unroll
    for (int j = 0; j < 2; ++j)
        GLOAD16(bS[j], &smem[4096 + (j * 512 + wv * 64) * 8]);
    if (nt > 1) {
        GLOAD16(aS + 32, &smem[12288 + dA]);
#pragma unroll
        for (int j = 0; j < 2; ++j)
            GLOAD16(bS[j] + 32, &smem[12288 + 4096 + (j * 512 + wv * 64) * 8]);
    }

    for (int ti = 0; ti < nt; ++ti) {
        if (ti + 1 < nt) {
            asm volatile("s_waitcnt vmcnt(3)" ::: "memory");
        } else {
            asm volatile("s_waitcnt vmcnt(0)" ::: "memory");
        }
        __builtin_amdgcn_s_barrier();

        const int cb = (ti & 1) * 12288;
        const u16* Ab = &smem[cb];
        const u16* Bb = &smem[cb + 4096];
        s8bf af[4], bfr[4];
#pragma unroll
        for (int i = 0; i < 4; ++i) {
            const int ra = wm + i * 16 + lr;
            const int rb = wn + i * 16 + lr;
            af[i]  = *reinterpret_cast<const s8bf*>(
                &Ab[(size_t)((ra << 2) | (lks ^ ((ra >> 1) & 3))) * 8]);
            bfr[i] = *reinterpret_cast<const s8bf*>(
                &Bb[(size_t)((rb << 2) | (lks ^ ((rb >> 1) & 3))) * 8]);
        }
#pragma unroll
        for (int i = 0; i < 4; ++i)
#pragma unroll
            for (int j = 0; j < 4; ++j)
                acc[i][j] = __builtin_amdgcn_mfma_f32_16x16x32_bf16(af[i], bfr[j], acc[i][j], 0, 0, 0);

        __builtin_amdgcn_s_barrier();

        if (ti + 2 < nt) {
            const int k2 = (ti + 2) << 5;
            GLOAD16(aS + k2, &smem[cb + dA]);
#pragma unroll
            for (int j = 0; j < 2; ++j)
                GLOAD16(bS[j] + k2, &smem[cb + 4096 + (j * 512 + wv * 64) * 8]);
        }
    }

    // ---- one-pass LDS-staged coalesced epilogue: C-tile 128x256 ----
    u16* Cs = smem;
#pragma unroll
    for (int i = 0; i < 4; ++i)
#pragma unroll
        for (int j = 0; j < 4; ++j) {
            const int col = wn + j * 16 + lr;            // 0..255
            const float bb = bias[n0 + col];
#pragma unroll
            for (int r = 0; r < 4; ++r) {
                const int row = wm + i * 16 + (lane >> 4) * 4 + r;   // 0..127
                float v = acc[i][j][r] + bb;
                if (ACT == 1) v = fast_gelu(v);
                if (ACT == 2) v = v > 0.f ? v : 0.f;
                const int xr = ((((row >> 2) & 3) ^ (row & 3)) << 4);
                Cs[(row << 8) | (col ^ xr)] = f2bf(v);
            }
        }
    __syncthreads();
#pragma unroll
    for (int it = 0; it < 8; ++it) {
        const int row = (t >> 5) + it * 16;              // 0..127
        const int gr  = m0 + row;
        const int q   = (t & 31) * 8;                    // 0..248
        const int xr  = ((((row >> 2) & 3) ^ (row & 3)) << 4);
        s8bf v = *reinterpret_cast<const s8bf*>(&Cs[(row << 8) | (q ^ xr)]);
        if (gr < M)
            *reinterpret_cast<s8bf*>(C + (size_t)gr * N + n0 + q) = v;
    }
}

// ---------------------------------------------------------------------------
// Bias concat for fused off+attn projection: b_cat[0:64)=b_off, [64:96)=b_attn
// ---------------------------------------------------------------------------
__global__ __launch_bounds__(128) void concat_bias_kernel(
    const float* __restrict__ b_off, const float* __restrict__ b_attn,
    float* __restrict__ b_cat)
{
    const int t = threadIdx.x;
    if (t < 64) b_cat[t] = b_off[t];
    else if (t < 96) b_cat[t] = b_attn[t - 64];
}

// ---------------------------------------------------------------------------
// Sampler v5 (r20, proven): bf16 value grid, ushort8 gathers.
// 16 queries/block, 256 threads, grid 2048.
// ---------------------------------------------------------------------------
__global__ __launch_bounds__(256) void sample_kernel(
    const float* __restrict__ proj, const u16* __restrict__ cpf16,
    u16* __restrict__ out)
{
    __shared__ float4 sW[16][32];
    __shared__ int4   sT[16][32];

    const int blk = blockIdx.x;
    const int b   = blk / (NQ_ / 16);
    const int q0  = (blk % (NQ_ / 16)) * 16;
    const int t   = threadIdx.x;

    for (int it = t; it < 16 * 32; it += 256) {   // 2 iterations
        const int qq = it >> 5, i = it & 31;
        const int h = i >> 2, p = i & 3;
        const size_t row = (size_t)b * NQ_ + q0 + qq;
        const float* pr = proj + row * 96;
        const float* lg = pr + 64 + h * 4;
        float l0 = lg[0], l1 = lg[1], l2 = lg[2], l3 = lg[3];
        float mx = fmaxf(fmaxf(l0, l1), fmaxf(l2, l3));
        float e0 = __expf(l0 - mx), e1 = __expf(l1 - mx);
        float e2 = __expf(l2 - mx), e3 = __expf(l3 - mx);
        float lp = (p == 0) ? l0 : (p == 1) ? l1 : (p == 2) ? l2 : l3;
        float aw = __expf(lp - mx) / (e0 + e1 + e2 + e3);
        float ox = pr[2 * i], oy = pr[2 * i + 1];
        float gx = 2.f * fast_sigmoid(ox) - 1.f;
        float gy = 2.f * fast_sigmoid(oy) - 1.f;
        float ix = ((gx + 1.f) * (float)GW_ - 1.f) * 0.5f;
        float iy = ((gy + 1.f) * (float)GW_ - 1.f) * 0.5f;
        float x0f = floorf(ix), y0f = floorf(iy);
        float wx1 = ix - x0f, wy1 = iy - y0f;
        float wx0 = 1.f - wx1, wy0 = 1.f - wy1;
        int xi = (int)x0f, yi = (int)y0f;
        bool vx0 = (xi >= 0) & (xi < GW_), vx1 = (xi + 1 >= 0) & (xi + 1 < GW_);
        bool vy0 = (yi >= 0) & (yi < GW_), vy1 = (yi + 1 >= 0) & (yi + 1 < GW_);
        float4 w;
        w.x = (vx0 & vy0) ? aw * wx0 * wy0 : 0.f;
        w.y = (vx1 & vy0) ? aw * wx1 * wy0 : 0.f;
        w.z = (vx0 & vy1) ? aw * wx0 * wy1 : 0.f;
        w.w = (vx1 & vy1) ? aw * wx1 * wy1 : 0.f;
        int cx0 = xi < 0 ? 0 : (xi > GW_ - 1 ? GW_ - 1 : xi);
        int cx1 = xi + 1 < 0 ? 0 : (xi + 1 > GW_ - 1 ? GW_ - 1 : xi + 1);
        int cy0 = yi < 0 ? 0 : (yi > GW_ - 1 ? GW_ - 1 : yi);
        int cy1 = yi + 1 < 0 ? 0 : (yi + 1 > GW_ - 1 ? GW_ - 1 : yi + 1);
        int4 tk;
        tk.x = cy0 * GW_ + cx0; tk.y = cy0 * GW_ + cx1;
        tk.z = cy1 * GW_ + cx0; tk.w = cy1 * GW_ + cx1;
        sW[qq][i] = w; sT[qq][i] = tk;
    }
    __syncthreads();

    const s8bf* vb8 = reinterpret_cast<const s8bf*>(cpf16 + (size_t)b * NT_ * D_ + D_);
    for (int idx = t; idx < 16 * 48; idx += 256) {   // 3 iterations
        const int qq = idx / 48, c8 = idx % 48, h = c8 / 6;
        int4   tk0 = sT[qq][h * 4 + 0], tk1 = sT[qq][h * 4 + 1];
        int4   tk2 = sT[qq][h * 4 + 2], tk3 = sT[qq][h * 4 + 3];
        float4 w0  = sW[qq][h * 4 + 0], w1  = sW[qq][h * 4 + 1];
        float4 w2  = sW[qq][h * 4 + 2], w3  = sW[qq][h * 4 + 3];
        s8bf v00 = vb8[(size_t)tk0.x * 48 + c8], v01 = vb8[(size_t)tk0.y * 48 + c8];
        s8bf v02 = vb8[(size_t)tk0.z * 48 + c8], v03 = vb8[(size_t)tk0.w * 48 + c8];
        s8bf v10 = vb8[(size_t)tk1.x * 48 + c8], v11 = vb8[(size_t)tk1.y * 48 + c8];
        s8bf v12 = vb8[(size_t)tk1.z * 48 + c8], v13 = vb8[(size_t)tk1.w * 48 + c8];
        s8bf v20 = vb8[(size_t)tk2.x * 48 + c8], v21 = vb8[(size_t)tk2.y * 48 + c8];
        s8bf v22 = vb8[(size_t)tk2.z * 48 + c8], v23 = vb8[(size_t)tk2.w * 48 + c8];
        s8bf v30 = vb8[(size_t)tk3.x * 48 + c8], v31 = vb8[(size_t)tk3.y * 48 + c8];
        s8bf v32 = vb8[(size_t)tk3.z * 48 + c8], v33 = vb8[(size_t)tk3.w * 48 + c8];
        float oA[8] = {0.f,0.f,0.f,0.f,0.f,0.f,0.f,0.f};
        float oB[8] = {0.f,0.f,0.f,0.f,0.f,0.f,0.f,0.f};
        fmacc8(oA, v00, w0.x); fmacc8(oB, v01, w0.y);
        fmacc8(oA, v02, w0.z); fmacc8(oB, v03, w0.w);
        fmacc8(oA, v10, w1.x); fmacc8(oB, v11, w1.y);
        fmacc8(oA, v12, w1.z); fmacc8(oB, v13, w1.w);
        fmacc8(oA, v20, w2.x); fmacc8(oB, v21, w2.y);
        fmacc8(oA, v22, w2.z); fmacc8(oB, v23, w2.w);
        fmacc8(oA, v30, w3.x); fmacc8(oB, v31, w3.y);
        fmacc8(oA, v32, w3.z); fmacc8(oB, v33, w3.w);
        s8bf pk;
#pragma unroll
        for (int k = 0; k < 8; ++k) pk[k] = (short)f2bf(oA[k] + oB[k]);
        *reinterpret_cast<s8bf*>(&out[((size_t)b * NQ_ + q0 + qq) * D_ + c8 * 8]) = pk;
    }
}

// ---------------------------------------------------------------------------
// Gate reduce: gate[row] = sigmoid(dot(gh[row,0:96], Wg2) + bg2).
// ---------------------------------------------------------------------------
__global__ __launch_bounds__(256) void gate_reduce_kernel(
    const float* __restrict__ gh, const float* __restrict__ Wg2,
    const float* __restrict__ bg2, float* __restrict__ gate_out)
{
    const int wave = threadIdx.x >> 6, lane = threadIdx.x & 63;
    const size_t row = (size_t)blockIdx.x * 4 + wave;
    const float* h = gh + row * 96;
    float s = h[lane] * Wg2[lane];
    if (lane < 32) s += h[64 + lane] * Wg2[64 + lane];
#pragma unroll
    for (int o = 32; o > 0; o >>= 1) s += __shfl_down(s, o);
    if (lane == 0) gate_out[row] = 1.f / (1.f + expf(-(s + bg2[0])));
}

// ---------------------------------------------------------------------------
extern "C" void kernel_launch(void* const* d_in, const int* in_sizes, int n_in,
                              void* d_out, int out_size, void* d_ws, size_t ws_size,
                              hipStream_t stream)
{
    const float* visual = (const float*)d_in[0];
    const float* cut3r  = (const float*)d_in[1];
    const float* ln_v_g = (const float*)d_in[2];
    const float* ln_v_b = (const float*)d_in[3];
    const float* ln_c_g = (const float*)d_in[4];
    const float* ln_c_b = (const float*)d_in[5];
    const float* W_c1 = (const float*)d_in[6];
    const float* b_c1 = (const float*)d_in[7];
    const float* W_c2 = (const float*)d_in[8];
    const float* b_c2 = (const float*)d_in[9];
    const float* W_off = (const float*)d_in[10];
    const float* b_off = (const float*)d_in[11];
    const float* W_attn = (const float*)d_in[12];
    const float* b_attn = (const float*)d_in[13];
    const float* W_out = (const float*)d_in[14];
    const float* b_out = (const float*)d_in[15];
    const float* W_f1 = (const float*)d_in[16];
    const float* b_f1 = (const float*)d_in[17];
    const float* W_f2 = (const float*)d_in[18];
    const float* b_f2 = (const float*)d_in[19];
    const float* W_g1 = (const float*)d_in[20];
    const float* b_g1 = (const float*)d_in[21];
    const float* W_g2 = (const float*)d_in[22];
    const float* b_g2 = (const float*)d_in[23];
    const float* ln_o_g = (const float*)d_in[24];
    const float* ln_o_b = (const float*)d_in[25];

    // --- workspace layout (bytes); high-water ~86.8 MB (<=89.07 proven r3) ---
    char* ws = (char*)d_ws;
    u16*   vflat   = (u16*)(ws + 0);
    u16*   vn      = (u16*)(ws + 25165824);
    u16*   attn_out= (u16*)(ws + 25165824);
    u16*   chid    = (u16*)(ws + 50331648);
    u16*   dout    = (u16*)(ws + 50331648);
    u16*   ffn     = (u16*)(ws + 50331648);
    u16*   cpf16   = (u16*)(ws + 75497472);    // bf16 [B,730,384] = 4.49 MB
    u16*   wt_f1b  = (u16*)(ws + 84467712);    // [1536][384]
    u16*   wt_f2b  = wt_f1b + 589824;          // [384][1536]

    // --- d_out as scratch (fully overwritten by final steps) ---
    float* dout_f   = (float*)d_out;
    u16*   cn       = (u16*)d_out;
    float* proj_buf = dout_f;
    float* b_cat    = dout_f + 3145728;
    float* gate_hid = dout_f;
    u16*   hidden   = (u16*)d_out;
    char*  wtp      = (char*)d_out + 25165824;
    u16* wt_c1   = (u16*)wtp;                  // [768][1024]
    u16* wt_c2   = wt_c1 + 786432;             // [384][768]
    u16* wt_out  = wt_c2 + 294912;             // [384][384]
    u16* wt_g1   = wt_out + 147456;            // [96][384]
    u16* wt_off  = wt_g1 + 36864;              // [64][384]  \ contiguous [96][384]
    u16* wt_attn = wt_off + 24576;             // [32][384]  /
    float* out_fused = dout_f;
    float* out_gate  = dout_f + (size_t)B_ * D_ * NQ_;

    // 0. ALL weight conversions in one launch + bias concat
    WtArgs wa;
    int cum = 0;
    auto fill = [&](int i, const float* src, u16* dst, int R, int C) {
        wa.d[i].src = src; wa.d[i].dst = dst; wa.d[i].R = R; wa.d[i].C = C;
        wa.d[i].start = cum; cum += (R >> 5) * (C >> 5);
    };
    fill(0, W_c1,  wt_c1,  1024, 768);
    fill(1, W_c2,  wt_c2,  768,  384);
    fill(2, W_out, wt_out, 384,  384);
    fill(3, W_g1,  wt_g1,  384,  96);
    fill(4, W_off, wt_off, 384,  64);
    fill(5, W_attn,wt_attn,384,  32);
    fill(6, W_f1,  wt_f1b, 384,  1536);
    fill(7, W_f2,  wt_f2b, 1536, 384);
    hipLaunchKernelGGL(wt_convert_kernel, dim3(cum), dim3(256), 0, stream, wa);
    hipLaunchKernelGGL(concat_bias_kernel, dim3(1), dim3(128), 0, stream, b_off, b_attn, b_cat);

    // 1. fused visual transpose + LN -> vflat (raw) + vn (normalized)
    hipLaunchKernelGGL(tr_ln_kernel, dim3(1024), dim3(256), 0, stream,
                       visual, ln_v_g, ln_v_b, vflat, vn);
    // 2. LN(cut3r f32) -> cn bf16 (d_out scratch)
    hipLaunchKernelGGL(ln_kernel, dim3(5840), dim3(256), 0, stream,
                       cut3r, ln_c_g, ln_c_b, cn, 1024);
    // 3. gelu(cn @ W_c1 + b_c1) -> chid bf16   [5840 x 768 x 1024]
    hipLaunchKernelGGL((mfma_gemm<1, u16>), dim3(46, 6), dim3(256), 0, stream,
                       cn, wt_c1, b_c1, chid, 5840, 768, 1024);
    // 4. chid @ W_c2 + b_c2 -> cpf16 bf16 [B,730,384]   [5840 x 384 x 768]
    hipLaunchKernelGGL((mfma_gemm<0, u16>), dim3(46, 3), dim3(256), 0, stream,
                       chid, wt_c2, b_c2, cpf16, 5840, 384, 768);
    // 6. fused off+attn projection -> proj_buf f32 [32768 x 96 x 384] (cn dead)
    hipLaunchKernelGGL((mfma_gemm<0, float>), dim3(256, 1), dim3(256), 0, stream,
                       vn, wt_off, b_cat, proj_buf, 32768, 96, 384);
    // 7. sampler (bf16 values, ushort8 gathers) -> dout bf16 [B*Nq,384]
    hipLaunchKernelGGL(sample_kernel, dim3(2048), dim3(256), 0, stream,
                       proj_buf, cpf16, dout);
    // 8. dout @ W_out + b_out -> attn_out bf16   [32768 x 384 x 384] (vn dead)
    hipLaunchKernelGGL((mfma_gemm<0, u16>), dim3(256, 3), dim3(256), 0, stream,
                       dout, wt_out, b_out, attn_out, 32768, 384, 384);
    // 9. gate (proj_buf dead -> gate_hid reuses it)
    hipLaunchKernelGGL((mfma_gemm<2, float>), dim3(256, 1), dim3(256), 0, stream,
                       vflat, wt_g1, b_g1, gate_hid, 32768, 96, 384);
    hipLaunchKernelGGL(gate_reduce_kernel, dim3(8192), dim3(256), 0, stream,
                       gate_hid, W_g2, b_g2, out_gate);
    // 11. FFN in 2 row-chunks of 16384; f1 wide (r16), f2 on K64 kernel (r21)
    for (int c = 0; c < 2; ++c) {
        hipLaunchKernelGGL((mfma_gemm_wide<1>), dim3(128, 6), dim3(512), 0, stream,
                           attn_out + (size_t)c * 16384 * 384, wt_f1b, b_f1, hidden,
                           16384, 1536, 384);
        hipLaunchKernelGGL((mfma_gemm_k64<0>), dim3(128, 3), dim3(256), 0, stream,
                           hidden, wt_f2b, b_f2, ffn + (size_t)c * 16384 * 384,
                           16384, 384, 1536);
    }
    // 12. fused = LN(vflat + gate*ffn) written TRANSPOSED straight to d_out
    hipLaunchKernelGGL(fused_ln_tr_kernel, dim3(1024), dim3(256), 0, stream,
                       vflat, out_gate, ffn, ln_o_g, ln_o_b, out_fused);
}